// Round 5
// baseline (9022.772 us; speedup 1.0000x reference)
//
#include <hip/hip_runtime.h>
#include <hip/hip_bf16.h>

#define EPS 1e-6f
#define SCAL 5.0f

// ---- static device scratch (zero-init BSS, graph-capture safe) ----
#define OFF_MU     0
#define OFF_LINV   1024
#define OFF_MUA    3072
#define OFF_LINVA  4096
#define OFF_HSUM   6144
#define OFF_ALPHA  6656
#define OFF_REC    23040
#define OFF_R1     32768
#define OFF_R2     (OFF_R1 + 8388608)
#define OFF_R3     (OFF_R2 + 8388608)
#define OFF_P      OFF_R3
#define OFF_C      (OFF_R3 + 2097152)
#define WS_TOTAL   (OFF_R3 + 16777216)

__device__ float g_ws[WS_TOTAL];
__device__ int g_isbf16;

// runtime-dtype input load
__device__ __forceinline__ float ldin(const void* p, size_t i, int bf) {
    return bf ? __bfloat162float(((const __hip_bfloat16*)p)[i])
              : ((const float*)p)[i];
}

// ---------------- block reductions (blockDim.x == 256) ----------------
__device__ __forceinline__ float block_sum(float v) {
    __shared__ float sb[8];
    for (int off = 32; off; off >>= 1) v += __shfl_down(v, off, 64);
    int lane = threadIdx.x & 63, wid = threadIdx.x >> 6;
    __syncthreads();
    if (lane == 0) sb[wid] = v;
    __syncthreads();
    float r = 0.f;
    for (int i = 0; i < 4; ++i) r += sb[i];
    return r;
}

__device__ __forceinline__ float block_max(float v) {
    __shared__ float sb[8];
    for (int off = 32; off; off >>= 1) v = fmaxf(v, __shfl_down(v, off, 64));
    int lane = threadIdx.x & 63, wid = threadIdx.x >> 6;
    __syncthreads();
    if (lane == 0) sb[wid] = v;
    __syncthreads();
    float r = -1e30f;
    for (int i = 0; i < 4; ++i) r = fmaxf(r, sb[i]);
    return r;
}

// ---------------- dtype probe + init ----------------
// x is uniform[0,1]. If the buffer is really bf16, all bf16-interpreted values
// are <= 1. If it is fp32, odd halfwords are fp32 high-halves whose exponent
// field makes values >2 (or NaN) with overwhelming probability over 256 lanes.
__global__ void detect_k(const void* x) {
    const __hip_bfloat16* p = (const __hip_bfloat16*)x;
    int lane = threadIdx.x & 63;
    float v = 0.f;
    for (int i = lane; i < 256; i += 64) {
        float a = fabsf(__bfloat162float(p[i]));
        if (!(a <= 2.0f)) v = 1.f;          // catches big AND NaN
    }
    for (int off = 32; off; off >>= 1) v += __shfl_down(v, off, 64);
    if (lane == 0) {
        g_isbf16 = (v == 0.f) ? 1 : 0;
        g_ws[OFF_REC] = 0.f;
    }
}

// ---------------- conv1: stride-2, image [B,3,128,128] -> fp32 [B,64,64,64], relu
__global__ void conv_s2_k(const void* __restrict__ in,
                          const void* __restrict__ w,
                          const void* __restrict__ bias,
                          int out_off) {
    int bf = g_isbf16;
    float* out = g_ws + out_off;
    int pb = blockIdx.x & 15;
    int bc = blockIdx.x >> 4;
    int oc = bc & 63, b = bc >> 6;
    __shared__ float wl[27];
    if (threadIdx.x < 27) wl[threadIdx.x] = ldin(w, oc * 27 + threadIdx.x, bf);
    __syncthreads();
    int pix = pb * 256 + threadIdx.x;
    int y = pix >> 6, x = pix & 63;
    float acc = ldin(bias, oc, bf);
    size_t inb = (size_t)b * 3 * 16384;
    for (int ic = 0; ic < 3; ++ic) {
        size_t pbase = inb + ic * 16384;
        for (int dy = 0; dy < 3; ++dy) {
            int iy = 2 * y + dy;                  // SAME stride-2: pad_low=0, pad_high=1
            if (iy >= 128) continue;
            size_t qbase = pbase + iy * 128;
            for (int dx = 0; dx < 3; ++dx) {
                int ix = 2 * x + dx;
                if (ix >= 128) continue;
                acc += ldin(in, qbase + ix, bf) * wl[ic * 9 + dy * 3 + dx];
            }
        }
    }
    out[((size_t)b * 64 + oc) * 4096 + pix] = fmaxf(acc, 0.f);
}

// ---------------- generic 3x3 SAME conv on 64x64, fp32 in/out ----------------
__global__ void conv3x3_k(int in_off,
                          const void* __restrict__ w,
                          const void* __restrict__ bias,
                          int out_off, int Cin, int Cout, int relu) {
    int bf = g_isbf16;
    const float* in = g_ws + in_off;
    float* out = g_ws + out_off;
    int pb = blockIdx.x & 15;
    int bc = blockIdx.x >> 4;
    int oc = bc % Cout, b = bc / Cout;
    extern __shared__ float wl[];
    for (int i = threadIdx.x; i < Cin * 9; i += 256)
        wl[i] = ldin(w, oc * Cin * 9 + i, bf);
    __syncthreads();
    int pix = pb * 256 + threadIdx.x;
    int y = pix >> 6, x = pix & 63;
    const float* inb = in + (size_t)b * Cin * 4096 + pix;
    float acc = ldin(bias, oc, bf);
    bool ym = y > 0, yp = y < 63, xm = x > 0, xp = x < 63;
    for (int ic = 0; ic < Cin; ++ic) {
        const float* p = inb + ic * 4096;
        const float* wr = wl + ic * 9;
        if (ym) {
            if (xm) acc += p[-65] * wr[0];
            acc += p[-64] * wr[1];
            if (xp) acc += p[-63] * wr[2];
        }
        if (xm) acc += p[-1] * wr[3];
        acc += p[0] * wr[4];
        if (xp) acc += p[1] * wr[5];
        if (yp) {
            if (xm) acc += p[63] * wr[6];
            acc += p[64] * wr[7];
            if (xp) acc += p[65] * wr[8];
        }
    }
    if (relu) acc = fmaxf(acc, 0.f);
    out[((size_t)b * Cout + oc) * 4096 + pix] = acc;
}

// ---------------- spatial softmax in place: rows of 4096 ----------------
__global__ void softmax_k(int off) {
    float* row = g_ws + off + (size_t)blockIdx.x * 4096;
    float m = -1e30f;
    for (int i = threadIdx.x; i < 4096; i += 256) m = fmaxf(m, row[i]);
    m = block_max(m);
    float s = 0.f;
    for (int i = threadIdx.x; i < 4096; i += 256) s += __expf(row[i] - m);
    s = block_sum(s);
    float inv = 1.0f / s;
    for (int i = threadIdx.x; i < 4096; i += 256) row[i] = __expf(row[i] - m) * inv;
}

// ---------------- soft-argmax moments -> mu [bk,2], L_inv [bk,4] ----------------
__global__ void moments_k(int p_off, int mu_off, int linv_off) {
    int bk = blockIdx.x;
    const float* row = g_ws + p_off + (size_t)bk * 4096;
    float* mu = g_ws + mu_off;
    float* linv = g_ws + linv_off;
    float sy = 0, sx = 0, syy = 0, sxy = 0, sxx = 0;
    for (int i = threadIdx.x; i < 4096; i += 256) {
        float pv = row[i];
        float gy = -1.0f + (i >> 6) * (2.0f / 63.0f);
        float gx = -1.0f + (i & 63) * (2.0f / 63.0f);
        sy += pv * gy; sx += pv * gx;
        syy += pv * gy * gy; sxy += pv * gy * gx; sxx += pv * gx * gx;
    }
    sy = block_sum(sy); sx = block_sum(sx);
    syy = block_sum(syy); sxy = block_sum(sxy); sxx = block_sum(sxx);
    if (threadIdx.x == 0) {
        float c00 = syy - sy * sy, c01 = sxy - sy * sx, c11 = sxx - sx * sx;
        float a = sqrtf(fmaxf(c00 + EPS, 1e-12f));
        float bb = c01 / (a + EPS);
        float cc = sqrtf(fmaxf(c11 - bb * bb, 0.f) + EPS);
        float det = a * cc;
        float s = SCAL / (det + EPS);
        mu[bk * 2 + 0] = sy; mu[bk * 2 + 1] = sx;
        linv[bk * 4 + 0] = cc * s; linv[bk * 4 + 1] = 0.f;
        linv[bk * 4 + 2] = -bb * s; linv[bk * 4 + 3] = a * s;
    }
}

// ---------------- alpha[b,k,f] = sum_hw fxs[b,f,hw] * parts[b,k,hw] ----------------
__global__ void alpha_k(int fxs_off, int parts_off) {
    int bk = blockIdx.x;
    int b = bk >> 4;
    float* alpha = g_ws + OFF_ALPHA;
    __shared__ float pl[4096];
    const float* pr = g_ws + parts_off + (size_t)bk * 4096;
    for (int i = threadIdx.x; i < 4096; i += 256) pl[i] = pr[i];
    __syncthreads();
    const float* fb = g_ws + fxs_off + (size_t)b * 32 * 4096;
    for (int f = 0; f < 32; ++f) {
        const float* fr = fb + f * 4096;
        float s = 0.f;
        for (int i = threadIdx.x; i < 4096; i += 256) s += fr[i] * pl[i];
        s = block_sum(s);
        if (threadIdx.x == 0) alpha[bk * 32 + f] = s;
    }
}

// ---------------- heat into enc ch[0..16), plus per-(b,k) sums ----------------
__global__ void heat_k(int mu_off, int linv_off, int enc_off) {
    int bk = blockIdx.x;
    int b = bk >> 4, k = bk & 15;
    const float* mu = g_ws + mu_off;
    const float* linv = g_ws + linv_off;
    float m0 = mu[bk * 2], m1 = mu[bk * 2 + 1];
    float L00 = linv[bk * 4 + 0], L10 = linv[bk * 4 + 2], L11 = linv[bk * 4 + 3];
    float* out = g_ws + enc_off + ((size_t)b * 48 + k) * 4096;
    float s = 0.f;
    for (int i = threadIdx.x; i < 4096; i += 256) {
        float d0 = -1.0f + (i >> 6) * (2.0f / 63.0f) - m0;
        float d1 = -1.0f + (i & 63) * (2.0f / 63.0f) - m1;
        float p0 = d0 * L00 + d1 * L10;
        float p1 = d1 * L11;              // L01 == 0
        float h = 1.0f / (1.0f + p0 * p0 + p1 * p1);
        out[i] = h;
        s += h;
    }
    s = block_sum(s);
    if (threadIdx.x == 0) g_ws[OFF_HSUM + bk] = s;
}

// ---------------- fmap into enc ch[16..48) ----------------
__global__ void fmap_k(int enc_off) {
    int t = blockIdx.x;
    int tile = t & 15, bf = t >> 4;
    int f = bf & 31, b = bf >> 5;
    __shared__ float coef[16];
    if (threadIdx.x < 16) {
        int k = threadIdx.x;
        coef[k] = g_ws[OFF_ALPHA + (b * 16 + k) * 32 + f] /
                  (g_ws[OFF_HSUM + b * 16 + k] + EPS);
    }
    __syncthreads();
    int pix = tile * 256 + threadIdx.x;
    const float* hb = g_ws + enc_off + (size_t)b * 48 * 4096 + pix;
    float acc = 0.f;
    for (int k = 0; k < 16; ++k) acc += hb[k * 4096] * coef[k];
    g_ws[enc_off + ((size_t)b * 48 + 16 + f) * 4096 + pix] = acc;
}

// ---------------- decoder conv2 with fused 2x nearest upsample ----------------
__global__ void conv_up_k(int in_off,
                          const void* __restrict__ w,
                          const void* __restrict__ bias,
                          int out_off) {
    int bf = g_isbf16;
    const float* in = g_ws + in_off;
    float* out = g_ws + out_off;
    int pb = blockIdx.x & 63;
    int bc = blockIdx.x >> 6;
    int oc = bc & 31, b = bc >> 5;
    __shared__ float wl[576];
    for (int i = threadIdx.x; i < 576; i += 256) wl[i] = ldin(w, oc * 576 + i, bf);
    __syncthreads();
    int pix = pb * 256 + threadIdx.x;
    int y = pix >> 7, x = pix & 127;
    float acc = ldin(bias, oc, bf);
    const float* inb = in + (size_t)b * 64 * 4096;
    int ys[3], xs[3];
    bool yv[3], xv[3];
    for (int d = 0; d < 3; ++d) {
        int uy = y + d - 1; yv[d] = (uy >= 0 && uy < 128); ys[d] = (uy >= 0 ? uy : 0) >> 1;
        int ux = x + d - 1; xv[d] = (ux >= 0 && ux < 128); xs[d] = (ux >= 0 ? ux : 0) >> 1;
    }
    for (int ic = 0; ic < 64; ++ic) {
        const float* p = inb + ic * 4096;
        const float* wr = wl + ic * 9;
        for (int dy = 0; dy < 3; ++dy) {
            if (!yv[dy]) continue;
            const float* q = p + ys[dy] * 64;
            for (int dx = 0; dx < 3; ++dx)
                if (xv[dx]) acc += q[xs[dx]] * wr[dy * 3 + dx];
        }
    }
    out[((size_t)b * 32 + oc) * 16384 + pix] = fmaxf(acc, 0.f);
}

// ---------------- final conv + sigmoid -> out (dtype per flag), fused rec-loss ----------------
__global__ void conv_sig_k(int in_off,
                           const void* __restrict__ w,
                           const void* __restrict__ bias,
                           const void* __restrict__ ximg,
                           void* __restrict__ outp) {
    int bf = g_isbf16;
    const float* in = g_ws + in_off;
    int pb = blockIdx.x & 63;
    int bc = blockIdx.x >> 6;
    int oc = bc % 3, b = bc / 3;
    __shared__ float wl[288];
    for (int i = threadIdx.x; i < 288; i += 256) wl[i] = ldin(w, oc * 288 + i, bf);
    __syncthreads();
    int pix = pb * 256 + threadIdx.x;
    int y = pix >> 7, x = pix & 127;
    float acc = ldin(bias, oc, bf);
    const float* inb = in + (size_t)b * 32 * 16384 + pix;
    bool ym = y > 0, yp = y < 127, xm = x > 0, xp = x < 127;
    for (int ic = 0; ic < 32; ++ic) {
        const float* p = inb + ic * 16384;
        const float* wr = wl + ic * 9;
        if (ym) {
            if (xm) acc += p[-129] * wr[0];
            acc += p[-128] * wr[1];
            if (xp) acc += p[-127] * wr[2];
        }
        if (xm) acc += p[-1] * wr[3];
        acc += p[0] * wr[4];
        if (xp) acc += p[1] * wr[5];
        if (yp) {
            if (xm) acc += p[127] * wr[6];
            acc += p[128] * wr[7];
            if (xp) acc += p[129] * wr[8];
        }
    }
    float v = 1.0f / (1.0f + __expf(-acc));
    size_t oidx = ((size_t)b * 3 + oc) * 16384 + pix;
    if (bf) ((__hip_bfloat16*)outp)[oidx] = __float2bfloat16(v);
    else    ((float*)outp)[oidx] = v;
    float e = ldin(ximg, oidx, bf) - v;
    float s = block_sum(e * e);
    if (threadIdx.x == 0) atomicAdd(&g_ws[OFF_REC], s);
}

// ---------------- scalar loss ----------------
__global__ void loss_k(const void* __restrict__ coord,
                       const void* __restrict__ vec,
                       void* __restrict__ outp) {
    int bf = g_isbf16;
    const float* mu = g_ws + OFF_MU;
    const float* linv = g_ws + OFF_LINV;
    const float* mu_a = g_ws + OFF_MUA;
    const float* linv_a = g_ws + OFF_LINVA;
    float s1 = 0, s2 = 0, s3 = 0;
    for (int i = threadIdx.x; i < 1024; i += 256) {
        float d = mu[i] - mu_a[i];
        s1 += d * d;
        float t = ldin(coord, i, bf) + ldin(vec, i, bf);
        float d3 = mu_a[i] - t;
        s3 += d3 * d3;
    }
    for (int i = threadIdx.x; i < 2048; i += 256) {
        float d = linv[i] - linv_a[i];
        s2 += d * d;
    }
    s1 = block_sum(s1);
    s2 = block_sum(s2);
    s3 = block_sum(s3);
    if (threadIdx.x == 0) {
        float loss = g_ws[OFF_REC] / 1572864.0f + s1 / 1024.0f + 0.01f * (s2 / 2048.0f)
                   + s3 / 1024.0f;
        if (bf) ((__hip_bfloat16*)outp)[1572864] = __float2bfloat16(loss);
        else    ((float*)outp)[1572864] = loss;
    }
}

extern "C" void kernel_launch(void* const* d_in, const int* in_sizes, int n_in,
                              void* d_out, int out_size, void* d_ws, size_t ws_size,
                              hipStream_t stream) {
    const void* x     = d_in[0];
    const void* x_st  = d_in[1];
    const void* x_at  = d_in[2];
    const void* coord = d_in[3];
    const void* vec   = d_in[4];
    const void* es_w1 = d_in[5];
    const void* es_b1 = d_in[6];
    const void* es_w2 = d_in[7];
    const void* es_b2 = d_in[8];
    const void* es_wp = d_in[9];
    const void* es_bp = d_in[10];
    const void* ea_w1 = d_in[11];
    const void* ea_b1 = d_in[12];
    const void* ea_w2 = d_in[13];
    const void* ea_b2 = d_in[14];
    const void* d_w1  = d_in[15];
    const void* d_b1  = d_in[16];
    const void* d_w2  = d_in[17];
    const void* d_b2  = d_in[18];
    const void* d_w3  = d_in[19];
    const void* d_b3  = d_in[20];

    dim3 blk(256);
    detect_k<<<1, 64, 0, stream>>>(x);

    // ---- shape stream: e_sigma(x_appearance_transform) -> mu, L_inv ----
    conv_s2_k<<<32 * 64 * 16, blk, 0, stream>>>(x_at, es_w1, es_b1, OFF_R1);
    conv3x3_k<<<32 * 64 * 16, blk, 2304, stream>>>(OFF_R1, es_w2, es_b2, OFF_R2, 64, 64, 1);
    conv3x3_k<<<32 * 16 * 16, blk, 2304, stream>>>(OFF_R2, es_wp, es_bp, OFF_P, 64, 16, 0);
    softmax_k<<<512, blk, 0, stream>>>(OFF_P);
    moments_k<<<512, blk, 0, stream>>>(OFF_P, OFF_MU, OFF_LINV);

    // ---- appearance stream: e_sigma(x_spatial_transform) -> app_parts (P), app_sum (R2) ----
    conv_s2_k<<<32 * 64 * 16, blk, 0, stream>>>(x_st, es_w1, es_b1, OFF_R1);
    conv3x3_k<<<32 * 64 * 16, blk, 2304, stream>>>(OFF_R1, es_w2, es_b2, OFF_R2, 64, 64, 1);
    conv3x3_k<<<32 * 16 * 16, blk, 2304, stream>>>(OFF_R2, es_wp, es_bp, OFF_P, 64, 16, 0);
    softmax_k<<<512, blk, 0, stream>>>(OFF_P);
    moments_k<<<512, blk, 0, stream>>>(OFF_P, OFF_MUA, OFF_LINVA);

    // ---- e_alpha(app_sum=R2) -> f_xs (C), then alpha (uses app_parts P) ----
    conv3x3_k<<<32 * 64 * 16, blk, 2304, stream>>>(OFF_R2, ea_w1, ea_b1, OFF_R1, 64, 64, 1);
    conv3x3_k<<<32 * 32 * 16, blk, 2304, stream>>>(OFF_R1, ea_w2, ea_b2, OFF_C, 64, 32, 0);
    alpha_k<<<512, blk, 0, stream>>>(OFF_C, OFF_P);

    // ---- encoding into R1: heat (ch 0..15) + fmap (ch 16..47) ----
    heat_k<<<512, blk, 0, stream>>>(OFF_MU, OFF_LINV, OFF_R1);
    fmap_k<<<32 * 32 * 16, blk, 0, stream>>>(OFF_R1);

    // ---- decoder: E(R1) -> R2 -> D(R3) -> out ----
    conv3x3_k<<<32 * 64 * 16, blk, 1728, stream>>>(OFF_R1, d_w1, d_b1, OFF_R2, 48, 64, 1);
    conv_up_k<<<32 * 32 * 64, blk, 0, stream>>>(OFF_R2, d_w2, d_b2, OFF_R3);
    conv_sig_k<<<32 * 3 * 64, blk, 0, stream>>>(OFF_R3, d_w3, d_b3, x, d_out);

    // ---- loss ----
    loss_k<<<1, blk, 0, stream>>>(coord, vec, d_out);
}

// Round 8
// 2570.148 us; speedup vs baseline: 3.5106x; 3.5106x over previous
//
#include <hip/hip_runtime.h>
#include <hip/hip_bf16.h>

#define EPS 1e-6f
#define SCAL 5.0f

// ---- static device scratch (zero-init BSS, graph-capture safe) ----
#define OFF_MU     0
#define OFF_LINV   1024
#define OFF_MUA    3072
#define OFF_LINVA  4096
#define OFF_HSUM   6144
#define OFF_ALPHA  6656
#define OFF_REC    23040
#define OFF_W      32768
#define OFF_R1     (OFF_W + 262144)
#define OFF_R2     (OFF_R1 + 8388608)
#define OFF_R3     (OFF_R2 + 8388608)
#define OFF_P      OFF_R3
#define OFF_C      (OFF_R3 + 2097152)
#define WS_TOTAL   (OFF_R3 + 16777216)

// fp32 weight/bias offsets inside OFF_W (filled by wconv_k)
#define W_ESW1 (OFF_W + 0)
#define W_ESB1 (OFF_W + 1728)
#define W_ESW2 (OFF_W + 1792)
#define W_ESB2 (OFF_W + 38656)
#define W_ESWP (OFF_W + 38720)
#define W_ESBP (OFF_W + 47936)
#define W_EAW1 (OFF_W + 47952)
#define W_EAB1 (OFF_W + 84816)
#define W_EAW2 (OFF_W + 84880)
#define W_EAB2 (OFF_W + 103312)
#define W_DW1  (OFF_W + 103344)
#define W_DB1  (OFF_W + 130992)
#define W_DW2  (OFF_W + 131056)
#define W_DB2  (OFF_W + 149488)
#define W_DW3  (OFF_W + 149520)
#define W_DB3  (OFF_W + 150384)

__device__ float g_ws[WS_TOTAL];
__device__ int g_isbf16;

__device__ __forceinline__ float selz(bool c, float v) { return c ? v : 0.f; }

// runtime-dtype external load (the adaptive pattern that passed in round 5's bench)
__device__ __forceinline__ float ldin(const void* p, size_t i, int bf) {
    return bf ? __bfloat162float(((const __hip_bfloat16*)p)[i])
              : ((const float*)p)[i];
}

// ---------------- block reductions (blockDim.x == 256) ----------------
__device__ __forceinline__ float block_sum(float v) {
    __shared__ float sb[8];
    for (int off = 32; off; off >>= 1) v += __shfl_down(v, off, 64);
    int lane = threadIdx.x & 63, wid = threadIdx.x >> 6;
    __syncthreads();
    if (lane == 0) sb[wid] = v;
    __syncthreads();
    float r = 0.f;
    for (int i = 0; i < 4; ++i) r += sb[i];
    return r;
}

__device__ __forceinline__ float block_max(float v) {
    __shared__ float sb[8];
    for (int off = 32; off; off >>= 1) v = fmaxf(v, __shfl_down(v, off, 64));
    int lane = threadIdx.x & 63, wid = threadIdx.x >> 6;
    __syncthreads();
    if (lane == 0) sb[wid] = v;
    __syncthreads();
    float r = -1e30f;
    for (int i = 0; i < 4; ++i) r = fmaxf(r, sb[i]);
    return r;
}

// ---------------- dtype probe + init ----------------
// x is uniform[0,1]. bf16-interpreted values all <=1 if buffer is bf16; if it
// is fp32, odd halfwords are fp32 high-halves -> >2 or NaN with certainty
// over 256 samples.
__global__ void detect_k(const void* x) {
    const __hip_bfloat16* p = (const __hip_bfloat16*)x;
    int lane = threadIdx.x & 63;
    float v = 0.f;
    for (int i = lane; i < 256; i += 64) {
        float a = fabsf(__bfloat162float(p[i]));
        if (!(a <= 2.0f)) v = 1.f;          // catches big AND NaN
    }
    for (int off = 32; off; off >>= 1) v += __shfl_down(v, off, 64);
    if (lane == 0) {
        g_isbf16 = (v == 0.f) ? 1 : 0;
        g_ws[OFF_REC] = 0.f;
    }
}

// ---------------- weight prep: external dtype -> fp32 into g_ws[OFF_W..] ----------------
__global__ void wconv_k(const void* p0, const void* p1, const void* p2, const void* p3,
                        const void* p4, const void* p5, const void* p6, const void* p7,
                        const void* p8, const void* p9, const void* p10, const void* p11,
                        const void* p12, const void* p13, const void* p14, const void* p15) {
    int bf = g_isbf16;
    const void* ps[16] = {p0,p1,p2,p3,p4,p5,p6,p7,p8,p9,p10,p11,p12,p13,p14,p15};
    const int sz[16] = {1728,64,36864,64,9216,16,36864,64,18432,32,27648,64,18432,32,864,3};
    int gid = blockIdx.x * 256 + threadIdx.x, stride = gridDim.x * 256;
    int off = 0;
    for (int a = 0; a < 16; ++a) {
        const void* p = ps[a];
        for (int i = gid; i < sz[a]; i += stride)
            g_ws[OFF_W + off + i] = ldin(p, i, bf);
        off += sz[a];
    }
}

// ---------------- conv1: stride-2, image [B,3,128,128] -> fp32 [B,64,64,64], relu
// grid: B * (64/16) * 16 tiles; each thread: 1 pixel x 16 ocs
__global__ void conv_s2m_k(const void* __restrict__ in, int out_off) {
    int bf = g_isbf16;
    int tile = blockIdx.x & 15;
    int gb = blockIdx.x >> 4;
    int g = gb & 3, b = gb >> 2;
    int pix = tile * 256 + threadIdx.x;
    int y = pix >> 6, x = pix & 63;
    size_t inb = (size_t)b * 3 * 16384;
    const float* W = g_ws + W_ESW1 + (size_t)(g * 16) * 27;
    float acc[16];
    #pragma unroll
    for (int o = 0; o < 16; ++o) acc[o] = g_ws[W_ESB1 + g * 16 + o];
    // SAME stride-2: taps (2y+dy, 2x+dx), dy,dx in [0,3); OOB only at high edge
    int iy0 = 2 * y, ix0 = 2 * x;
    bool my2 = (iy0 + 2 < 128), mx2 = (ix0 + 2 < 128);
    int iy2 = my2 ? iy0 + 2 : 127, ix2 = mx2 ? ix0 + 2 : 127;
    for (int ic = 0; ic < 3; ++ic) {
        size_t pb = inb + ic * 16384;
        float t[9];
        t[0] = ldin(in, pb + iy0 * 128 + ix0, bf);
        t[1] = ldin(in, pb + iy0 * 128 + ix0 + 1, bf);
        t[2] = selz(mx2, ldin(in, pb + iy0 * 128 + ix2, bf));
        t[3] = ldin(in, pb + (iy0 + 1) * 128 + ix0, bf);
        t[4] = ldin(in, pb + (iy0 + 1) * 128 + ix0 + 1, bf);
        t[5] = selz(mx2, ldin(in, pb + (iy0 + 1) * 128 + ix2, bf));
        t[6] = selz(my2, ldin(in, pb + iy2 * 128 + ix0, bf));
        t[7] = selz(my2, ldin(in, pb + iy2 * 128 + ix0 + 1, bf));
        t[8] = selz(my2 && mx2, ldin(in, pb + iy2 * 128 + ix2, bf));
        #pragma unroll
        for (int o = 0; o < 16; ++o) {
            const float* wr = W + (o * 3 + ic) * 9;
            float a = acc[o];
            #pragma unroll
            for (int j = 0; j < 9; ++j) a = fmaf(t[j], wr[j], a);
            acc[o] = a;
        }
    }
    float* out = g_ws + out_off + ((size_t)b * 64 + g * 16) * 4096 + pix;
    #pragma unroll
    for (int o = 0; o < 16; ++o) out[o * 4096] = fmaxf(acc[o], 0.f);
}

// ---------------- generic 3x3 SAME conv on 64x64 planes, fp32 in/out ----------------
// grid: B * ng * 16 tiles; each thread: 1 pixel x OCG ocs; weights via uniform loads
template<int CIN, int OCG>
__global__ void conv64_k(int in_off, int w_off, int b_off, int out_off,
                         int ng, int Cout, int relu) {
    int tile = blockIdx.x & 15;
    int gb = blockIdx.x >> 4;
    int g = gb % ng, b = gb / ng;
    int pix = tile * 256 + threadIdx.x;
    int y = pix >> 6, x = pix & 63;
    const float* inb = g_ws + in_off + (size_t)b * CIN * 4096;
    const float* W = g_ws + w_off + (size_t)(g * OCG) * CIN * 9;
    float acc[OCG];
    #pragma unroll
    for (int o = 0; o < OCG; ++o) acc[o] = g_ws[b_off + g * OCG + o];
    bool vy0 = (y > 0), vy2 = (y < 63), vx0 = (x > 0), vx2 = (x < 63);
    int rm = (vy0 ? y - 1 : 0) * 64, r0 = y * 64, rp = (vy2 ? y + 1 : 63) * 64;
    int cm = vx0 ? x - 1 : 0, cp = vx2 ? x + 1 : 63;
    for (int ic = 0; ic < CIN; ++ic) {
        const float* p = inb + ic * 4096;
        float t[9];
        t[0] = selz(vy0 && vx0, p[rm + cm]);
        t[1] = selz(vy0,        p[rm + x]);
        t[2] = selz(vy0 && vx2, p[rm + cp]);
        t[3] = selz(vx0,        p[r0 + cm]);
        t[4] =                  p[r0 + x];
        t[5] = selz(vx2,        p[r0 + cp]);
        t[6] = selz(vy2 && vx0, p[rp + cm]);
        t[7] = selz(vy2,        p[rp + x]);
        t[8] = selz(vy2 && vx2, p[rp + cp]);
        #pragma unroll
        for (int o = 0; o < OCG; ++o) {
            const float* wr = W + (o * CIN + ic) * 9;
            float a = acc[o];
            #pragma unroll
            for (int j = 0; j < 9; ++j) a = fmaf(t[j], wr[j], a);
            acc[o] = a;
        }
    }
    float* out = g_ws + out_off + ((size_t)b * Cout + g * OCG) * 4096 + pix;
    if (relu) {
        #pragma unroll
        for (int o = 0; o < OCG; ++o) out[o * 4096] = fmaxf(acc[o], 0.f);
    } else {
        #pragma unroll
        for (int o = 0; o < OCG; ++o) out[o * 4096] = acc[o];
    }
}

// ---------------- fused spatial softmax + moments; optionally write probs back ----------------
__global__ void sm_mom_k(int p_off, int mu_off, int linv_off, int write_p) {
    int bk = blockIdx.x;
    float* row = g_ws + p_off + (size_t)bk * 4096;
    float m = -1e30f;
    for (int i = threadIdx.x; i < 4096; i += 256) m = fmaxf(m, row[i]);
    m = block_max(m);
    float s = 0.f;
    for (int i = threadIdx.x; i < 4096; i += 256) s += __expf(row[i] - m);
    s = block_sum(s);
    float inv = 1.0f / s;
    float sy = 0, sx = 0, syy = 0, sxy = 0, sxx = 0;
    for (int i = threadIdx.x; i < 4096; i += 256) {
        float pv = __expf(row[i] - m) * inv;
        if (write_p) row[i] = pv;
        float gy = -1.0f + (i >> 6) * (2.0f / 63.0f);
        float gx = -1.0f + (i & 63) * (2.0f / 63.0f);
        sy += pv * gy; sx += pv * gx;
        syy += pv * gy * gy; sxy += pv * gy * gx; sxx += pv * gx * gx;
    }
    sy = block_sum(sy); sx = block_sum(sx);
    syy = block_sum(syy); sxy = block_sum(sxy); sxx = block_sum(sxx);
    if (threadIdx.x == 0) {
        float c00 = syy - sy * sy, c01 = sxy - sy * sx, c11 = sxx - sx * sx;
        float a = sqrtf(fmaxf(c00 + EPS, 1e-12f));
        float bb = c01 / (a + EPS);
        float cc = sqrtf(fmaxf(c11 - bb * bb, 0.f) + EPS);
        float det = a * cc;
        float sc = SCAL / (det + EPS);
        g_ws[mu_off + bk * 2 + 0] = sy;
        g_ws[mu_off + bk * 2 + 1] = sx;
        g_ws[linv_off + bk * 4 + 0] = cc * sc;
        g_ws[linv_off + bk * 4 + 1] = 0.f;
        g_ws[linv_off + bk * 4 + 2] = -bb * sc;
        g_ws[linv_off + bk * 4 + 3] = a * sc;
    }
}

// ---------------- alpha[b,k,f] = sum_hw fxs[b,f,hw] * parts[b,k,hw] ----------------
__global__ void alpha_k(int fxs_off, int parts_off) {
    int bk = blockIdx.x;
    int b = bk >> 4;
    float* alpha = g_ws + OFF_ALPHA;
    __shared__ float pl[4096];
    const float* pr = g_ws + parts_off + (size_t)bk * 4096;
    for (int i = threadIdx.x; i < 4096; i += 256) pl[i] = pr[i];
    __syncthreads();
    const float* fb = g_ws + fxs_off + (size_t)b * 32 * 4096;
    for (int f = 0; f < 32; ++f) {
        const float* fr = fb + f * 4096;
        float s = 0.f;
        for (int i = threadIdx.x; i < 4096; i += 256) s += fr[i] * pl[i];
        s = block_sum(s);
        if (threadIdx.x == 0) alpha[bk * 32 + f] = s;
    }
}

// ---------------- heat into enc ch[0..16), plus per-(b,k) sums ----------------
__global__ void heat_k(int mu_off, int linv_off, int enc_off) {
    int bk = blockIdx.x;
    int b = bk >> 4, k = bk & 15;
    float m0 = g_ws[mu_off + bk * 2], m1 = g_ws[mu_off + bk * 2 + 1];
    float L00 = g_ws[linv_off + bk * 4 + 0], L10 = g_ws[linv_off + bk * 4 + 2],
          L11 = g_ws[linv_off + bk * 4 + 3];
    float* out = g_ws + enc_off + ((size_t)b * 48 + k) * 4096;
    float s = 0.f;
    for (int i = threadIdx.x; i < 4096; i += 256) {
        float d0 = -1.0f + (i >> 6) * (2.0f / 63.0f) - m0;
        float d1 = -1.0f + (i & 63) * (2.0f / 63.0f) - m1;
        float p0 = d0 * L00 + d1 * L10;
        float p1 = d1 * L11;              // L01 == 0
        float h = 1.0f / (1.0f + p0 * p0 + p1 * p1);
        out[i] = h;
        s += h;
    }
    s = block_sum(s);
    if (threadIdx.x == 0) g_ws[OFF_HSUM + bk] = s;
}

// ---------------- fmap into enc ch[16..48) ----------------
__global__ void fmap_k(int enc_off) {
    int t = blockIdx.x;
    int tile = t & 15, bfi = t >> 4;
    int f = bfi & 31, b = bfi >> 5;
    __shared__ float coef[16];
    if (threadIdx.x < 16) {
        int k = threadIdx.x;
        coef[k] = g_ws[OFF_ALPHA + (b * 16 + k) * 32 + f] /
                  (g_ws[OFF_HSUM + b * 16 + k] + EPS);
    }
    __syncthreads();
    int pix = tile * 256 + threadIdx.x;
    const float* hb = g_ws + enc_off + (size_t)b * 48 * 4096 + pix;
    float acc = 0.f;
    for (int k = 0; k < 16; ++k) acc += hb[k * 4096] * coef[k];
    g_ws[enc_off + ((size_t)b * 48 + 16 + f) * 4096 + pix] = acc;
}

// ---------------- decoder conv2 + fused 2x nearest upsample ----------------
// in fp32 [B,64,64,64] (read as 128x128 upsampled), out fp32 [B,32,128,128], relu
// grid: B * 2 groups * 64 tiles; each thread: 1 pixel x 16 ocs
__global__ void conv_upm_k(int in_off, int out_off) {
    int tile = blockIdx.x & 63;
    int gb = blockIdx.x >> 6;
    int g = gb & 1, b = gb >> 1;
    int pix = tile * 256 + threadIdx.x;
    int y = pix >> 7, x = pix & 127;
    const float* inb = g_ws + in_off + (size_t)b * 64 * 4096;
    const float* W = g_ws + W_DW2 + (size_t)(g * 16) * 576;
    float acc[16];
    #pragma unroll
    for (int o = 0; o < 16; ++o) acc[o] = g_ws[W_DB2 + g * 16 + o];
    int ys[3], xs[3];
    bool yv[3], xv[3];
    #pragma unroll
    for (int d = 0; d < 3; ++d) {
        int uy = y + d - 1; yv[d] = (uy >= 0 && uy < 128); ys[d] = ((uy >= 0 ? (uy < 128 ? uy : 127) : 0) >> 1) * 64;
        int ux = x + d - 1; xv[d] = (ux >= 0 && ux < 128); xs[d] = (ux >= 0 ? (ux < 128 ? ux : 127) : 0) >> 1;
    }
    for (int ic = 0; ic < 64; ++ic) {
        const float* p = inb + ic * 4096;
        float t[9];
        #pragma unroll
        for (int dy = 0; dy < 3; ++dy)
            #pragma unroll
            for (int dx = 0; dx < 3; ++dx)
                t[dy * 3 + dx] = selz(yv[dy] && xv[dx], p[ys[dy] + xs[dx]]);
        #pragma unroll
        for (int o = 0; o < 16; ++o) {
            const float* wr = W + (o * 64 + ic) * 9;
            float a = acc[o];
            #pragma unroll
            for (int j = 0; j < 9; ++j) a = fmaf(t[j], wr[j], a);
            acc[o] = a;
        }
    }
    float* out = g_ws + out_off + ((size_t)b * 32 + g * 16) * 16384 + pix;
    #pragma unroll
    for (int o = 0; o < 16; ++o) out[o * 16384] = fmaxf(acc[o], 0.f);
}

// ---------------- final conv + sigmoid -> out (dtype per flag), fused rec-loss ----------------
// grid: B * 64 tiles; each thread: 1 pixel x 3 ocs
__global__ void conv_sigm_k(int in_off, const void* __restrict__ ximg,
                            void* __restrict__ outp) {
    int bf = g_isbf16;
    int tile = blockIdx.x & 63;
    int b = blockIdx.x >> 6;
    int pix = tile * 256 + threadIdx.x;
    int y = pix >> 7, x = pix & 127;
    const float* inb = g_ws + in_off + (size_t)b * 32 * 16384 + pix;
    const float* W = g_ws + W_DW3;
    float acc[3];
    #pragma unroll
    for (int o = 0; o < 3; ++o) acc[o] = g_ws[W_DB3 + o];
    bool vy0 = (y > 0), vy2 = (y < 127), vx0 = (x > 0), vx2 = (x < 127);
    int rm = vy0 ? -128 : 0, rp = vy2 ? 128 : 0;
    int cm = vx0 ? -1 : 0, cp = vx2 ? 1 : 0;
    for (int ic = 0; ic < 32; ++ic) {
        const float* p = inb + ic * 16384;
        float t[9];
        t[0] = selz(vy0 && vx0, p[rm + cm]);
        t[1] = selz(vy0,        p[rm]);
        t[2] = selz(vy0 && vx2, p[rm + cp]);
        t[3] = selz(vx0,        p[cm]);
        t[4] =                  p[0];
        t[5] = selz(vx2,        p[cp]);
        t[6] = selz(vy2 && vx0, p[rp + cm]);
        t[7] = selz(vy2,        p[rp]);
        t[8] = selz(vy2 && vx2, p[rp + cp]);
        #pragma unroll
        for (int o = 0; o < 3; ++o) {
            const float* wr = W + (o * 32 + ic) * 9;
            float a = acc[o];
            #pragma unroll
            for (int j = 0; j < 9; ++j) a = fmaf(t[j], wr[j], a);
            acc[o] = a;
        }
    }
    float es = 0.f;
    #pragma unroll
    for (int o = 0; o < 3; ++o) {
        float v = 1.0f / (1.0f + __expf(-acc[o]));
        size_t oidx = ((size_t)b * 3 + o) * 16384 + pix;
        if (bf) ((__hip_bfloat16*)outp)[oidx] = __float2bfloat16(v);
        else    ((float*)outp)[oidx] = v;
        float e = ldin(ximg, oidx, bf) - v;
        es += e * e;
    }
    float s = block_sum(es);
    if (threadIdx.x == 0) atomicAdd(&g_ws[OFF_REC], s);
}

// ---------------- scalar loss ----------------
__global__ void loss_k(const void* __restrict__ coord,
                       const void* __restrict__ vec,
                       void* __restrict__ outp) {
    int bf = g_isbf16;
    const float* mu = g_ws + OFF_MU;
    const float* linv = g_ws + OFF_LINV;
    const float* mu_a = g_ws + OFF_MUA;
    const float* linv_a = g_ws + OFF_LINVA;
    float s1 = 0, s2 = 0, s3 = 0;
    for (int i = threadIdx.x; i < 1024; i += 256) {
        float d = mu[i] - mu_a[i];
        s1 += d * d;
        float t = ldin(coord, i, bf) + ldin(vec, i, bf);
        float d3 = mu_a[i] - t;
        s3 += d3 * d3;
    }
    for (int i = threadIdx.x; i < 2048; i += 256) {
        float d = linv[i] - linv_a[i];
        s2 += d * d;
    }
    s1 = block_sum(s1);
    s2 = block_sum(s2);
    s3 = block_sum(s3);
    if (threadIdx.x == 0) {
        float loss = g_ws[OFF_REC] / 1572864.0f + s1 / 1024.0f + 0.01f * (s2 / 2048.0f)
                   + s3 / 1024.0f;
        if (bf) ((__hip_bfloat16*)outp)[1572864] = __float2bfloat16(loss);
        else    ((float*)outp)[1572864] = loss;
    }
}

extern "C" void kernel_launch(void* const* d_in, const int* in_sizes, int n_in,
                              void* d_out, int out_size, void* d_ws, size_t ws_size,
                              hipStream_t stream) {
    const void* x     = d_in[0];
    const void* x_st  = d_in[1];
    const void* x_at  = d_in[2];
    const void* coord = d_in[3];
    const void* vec   = d_in[4];

    dim3 blk(256);

    // dtype probe + rec zero, then weights -> fp32 (order matches W_* offsets)
    detect_k<<<1, 64, 0, stream>>>(x);
    wconv_k<<<64, blk, 0, stream>>>(
        d_in[5],  d_in[6],  d_in[7],  d_in[8],
        d_in[9],  d_in[10], d_in[11], d_in[12],
        d_in[13], d_in[14], d_in[15], d_in[16],
        d_in[17], d_in[18], d_in[19], d_in[20]);

    // ---- shape stream: e_sigma(x_appearance_transform) -> mu, L_inv ----
    conv_s2m_k<<<32 * 4 * 16, blk, 0, stream>>>(x_at, OFF_R1);
    conv64_k<64, 16><<<32 * 4 * 16, blk, 0, stream>>>(OFF_R1, W_ESW2, W_ESB2, OFF_R2, 4, 64, 1);
    conv64_k<64, 16><<<32 * 1 * 16, blk, 0, stream>>>(OFF_R2, W_ESWP, W_ESBP, OFF_P, 1, 16, 0);
    sm_mom_k<<<512, blk, 0, stream>>>(OFF_P, OFF_MU, OFF_LINV, 0);

    // ---- appearance stream -> app_parts (P), app_sum (R2) ----
    conv_s2m_k<<<32 * 4 * 16, blk, 0, stream>>>(x_st, OFF_R1);
    conv64_k<64, 16><<<32 * 4 * 16, blk, 0, stream>>>(OFF_R1, W_ESW2, W_ESB2, OFF_R2, 4, 64, 1);
    conv64_k<64, 16><<<32 * 1 * 16, blk, 0, stream>>>(OFF_R2, W_ESWP, W_ESBP, OFF_P, 1, 16, 0);
    sm_mom_k<<<512, blk, 0, stream>>>(OFF_P, OFF_MUA, OFF_LINVA, 1);

    // ---- e_alpha(app_sum=R2) -> f_xs (C), then alpha ----
    conv64_k<64, 16><<<32 * 4 * 16, blk, 0, stream>>>(OFF_R2, W_EAW1, W_EAB1, OFF_R1, 4, 64, 1);
    conv64_k<64, 16><<<32 * 2 * 16, blk, 0, stream>>>(OFF_R1, W_EAW2, W_EAB2, OFF_C, 2, 32, 0);
    alpha_k<<<512, blk, 0, stream>>>(OFF_C, OFF_P);

    // ---- encoding into R1: heat (ch 0..15) + fmap (ch 16..47) ----
    heat_k<<<512, blk, 0, stream>>>(OFF_MU, OFF_LINV, OFF_R1);
    fmap_k<<<32 * 32 * 16, blk, 0, stream>>>(OFF_R1);

    // ---- decoder: E(R1) -> R2 -> R3 -> out ----
    conv64_k<48, 16><<<32 * 4 * 16, blk, 0, stream>>>(OFF_R1, W_DW1, W_DB1, OFF_R2, 4, 64, 1);
    conv_upm_k<<<32 * 2 * 64, blk, 0, stream>>>(OFF_R2, OFF_R3);   // P,C dead now
    conv_sigm_k<<<32 * 64, blk, 0, stream>>>(OFF_R3, x, d_out);

    // ---- loss ----
    loss_k<<<1, blk, 0, stream>>>(coord, vec, d_out);
}

// Round 9
// 2301.473 us; speedup vs baseline: 3.9204x; 1.1167x over previous
//
#include <hip/hip_runtime.h>
#include <hip/hip_bf16.h>

#define EPS 1e-6f
#define SCAL 5.0f

// ---- static device scratch (zero-init BSS, graph-capture safe) ----
#define OFF_MU     0
#define OFF_LINV   1024
#define OFF_MUA    3072
#define OFF_LINVA  4096
#define OFF_HSUM   6144
#define OFF_ALPHA  6656
#define OFF_REC    23040
#define OFF_W      32768
#define OFF_R1     (OFF_W + 262144)
#define OFF_R2     (OFF_R1 + 8388608)
#define OFF_R3     (OFF_R2 + 8388608)
#define OFF_P      OFF_R3
#define OFF_C      (OFF_R3 + 2097152)
#define WS_TOTAL   (OFF_R3 + 16777216)

// fp32 weight/bias offsets inside OFF_W (filled by wconv_k)
#define W_ESW1 (OFF_W + 0)
#define W_ESB1 (OFF_W + 1728)
#define W_ESW2 (OFF_W + 1792)
#define W_ESB2 (OFF_W + 38656)
#define W_ESWP (OFF_W + 38720)
#define W_ESBP (OFF_W + 47936)
#define W_EAW1 (OFF_W + 47952)
#define W_EAB1 (OFF_W + 84816)
#define W_EAW2 (OFF_W + 84880)
#define W_EAB2 (OFF_W + 103312)
#define W_DW1  (OFF_W + 103344)
#define W_DB1  (OFF_W + 130992)
#define W_DW2  (OFF_W + 131056)
#define W_DB2  (OFF_W + 149488)
#define W_DW3  (OFF_W + 149520)
#define W_DB3  (OFF_W + 150384)

__device__ __attribute__((aligned(16))) float g_ws[WS_TOTAL];
__device__ int g_isbf16;

__device__ __forceinline__ float selz(bool c, float v) { return c ? v : 0.f; }

// runtime-dtype external load (adaptive pattern — required: fixed-dtype builds NaN'd)
__device__ __forceinline__ float ldin(const void* p, size_t i, int bf) {
    return bf ? __bfloat162float(((const __hip_bfloat16*)p)[i])
              : ((const float*)p)[i];
}

// ---------------- block reductions (blockDim.x == 256) ----------------
__device__ __forceinline__ float block_sum(float v) {
    __shared__ float sb[8];
    for (int off = 32; off; off >>= 1) v += __shfl_down(v, off, 64);
    int lane = threadIdx.x & 63, wid = threadIdx.x >> 6;
    __syncthreads();
    if (lane == 0) sb[wid] = v;
    __syncthreads();
    float r = 0.f;
    for (int i = 0; i < 4; ++i) r += sb[i];
    return r;
}

__device__ __forceinline__ float block_max(float v) {
    __shared__ float sb[8];
    for (int off = 32; off; off >>= 1) v = fmaxf(v, __shfl_down(v, off, 64));
    int lane = threadIdx.x & 63, wid = threadIdx.x >> 6;
    __syncthreads();
    if (lane == 0) sb[wid] = v;
    __syncthreads();
    float r = -1e30f;
    for (int i = 0; i < 4; ++i) r = fmaxf(r, sb[i]);
    return r;
}

// ---------------- dtype probe + init ----------------
__global__ void detect_k(const void* x) {
    const __hip_bfloat16* p = (const __hip_bfloat16*)x;
    int lane = threadIdx.x & 63;
    float v = 0.f;
    for (int i = lane; i < 256; i += 64) {
        float a = fabsf(__bfloat162float(p[i]));
        if (!(a <= 2.0f)) v = 1.f;          // catches big AND NaN
    }
    for (int off = 32; off; off >>= 1) v += __shfl_down(v, off, 64);
    if (lane == 0) {
        g_isbf16 = (v == 0.f) ? 1 : 0;
        g_ws[OFF_REC] = 0.f;
    }
}

// ---------------- weight prep: external dtype -> fp32 into g_ws[OFF_W..] ----------------
__global__ void wconv_k(const void* p0, const void* p1, const void* p2, const void* p3,
                        const void* p4, const void* p5, const void* p6, const void* p7,
                        const void* p8, const void* p9, const void* p10, const void* p11,
                        const void* p12, const void* p13, const void* p14, const void* p15) {
    int bf = g_isbf16;
    const void* ps[16] = {p0,p1,p2,p3,p4,p5,p6,p7,p8,p9,p10,p11,p12,p13,p14,p15};
    const int sz[16] = {1728,64,36864,64,9216,16,36864,64,18432,32,27648,64,18432,32,864,3};
    int gid = blockIdx.x * 256 + threadIdx.x, stride = gridDim.x * 256;
    int off = 0;
    for (int a = 0; a < 16; ++a) {
        const void* p = ps[a];
        for (int i = gid; i < sz[a]; i += stride)
            g_ws[OFF_W + off + i] = ldin(p, i, bf);
        off += sz[a];
    }
}

// ---------------- conv1: stride-2, image [B,3,128,128] -> fp32 [B,64,64,64], relu
__global__ void conv_s2m_k(const void* __restrict__ in, int out_off) {
    int bf = g_isbf16;
    int tile = blockIdx.x & 15;
    int gb = blockIdx.x >> 4;
    int g = gb & 3, b = gb >> 2;
    int pix = tile * 256 + threadIdx.x;
    int y = pix >> 6, x = pix & 63;
    size_t inb = (size_t)b * 3 * 16384;
    const float* W = g_ws + W_ESW1 + (size_t)(g * 16) * 27;
    float acc[16];
    #pragma unroll
    for (int o = 0; o < 16; ++o) acc[o] = g_ws[W_ESB1 + g * 16 + o];
    int iy0 = 2 * y, ix0 = 2 * x;
    bool my2 = (iy0 + 2 < 128), mx2 = (ix0 + 2 < 128);
    int iy2 = my2 ? iy0 + 2 : 127, ix2 = mx2 ? ix0 + 2 : 127;
    for (int ic = 0; ic < 3; ++ic) {
        size_t pb = inb + ic * 16384;
        float t[9];
        t[0] = ldin(in, pb + iy0 * 128 + ix0, bf);
        t[1] = ldin(in, pb + iy0 * 128 + ix0 + 1, bf);
        t[2] = selz(mx2, ldin(in, pb + iy0 * 128 + ix2, bf));
        t[3] = ldin(in, pb + (iy0 + 1) * 128 + ix0, bf);
        t[4] = ldin(in, pb + (iy0 + 1) * 128 + ix0 + 1, bf);
        t[5] = selz(mx2, ldin(in, pb + (iy0 + 1) * 128 + ix2, bf));
        t[6] = selz(my2, ldin(in, pb + iy2 * 128 + ix0, bf));
        t[7] = selz(my2, ldin(in, pb + iy2 * 128 + ix0 + 1, bf));
        t[8] = selz(my2 && mx2, ldin(in, pb + iy2 * 128 + ix2, bf));
        #pragma unroll
        for (int o = 0; o < 16; ++o) {
            const float* wr = W + (o * 3 + ic) * 9;
            float a = acc[o];
            #pragma unroll
            for (int j = 0; j < 9; ++j) a = fmaf(t[j], wr[j], a);
            acc[o] = a;
        }
    }
    float* out = g_ws + out_off + ((size_t)b * 64 + g * 16) * 4096 + pix;
    #pragma unroll
    for (int o = 0; o < 16; ++o) out[o * 4096] = fmaxf(acc[o], 0.f);
}

// ---------------- tiled 3x3 SAME conv on 64x64 planes: 1x4 px x OCG ocs per thread ----
// grid: 32b * ng * 4by; block 256 = 16 rows x 16 xq
template<int CIN, int OCG>
__global__ void conv64t_k(int in_off, int w_off, int b_off, int out_off,
                          int ng, int Cout, int relu) {
    int by = blockIdx.x & 3;
    int gb = blockIdx.x >> 2;
    int g = gb % ng, b = gb / ng;
    int xq = threadIdx.x & 15, ry = threadIdx.x >> 4;
    int y = by * 16 + ry, x0 = xq * 4;
    const float* inb = g_ws + in_off + (size_t)b * CIN * 4096;
    const float* W = g_ws + w_off + (size_t)(g * OCG) * CIN * 9;
    float acc[OCG][4];
    #pragma unroll
    for (int o = 0; o < OCG; ++o) {
        float bv = g_ws[b_off + g * OCG + o];
        #pragma unroll
        for (int p = 0; p < 4; ++p) acc[o][p] = bv;
    }
    bool ym = y > 0, yp = y < 63, xm = x0 > 0, xp = x0 < 60;
    int rm = (ym ? y - 1 : 0) * 64, r0 = y * 64, rp = (yp ? y + 1 : 63) * 64;
    int cxm = xm ? x0 - 1 : 0, cxp = xp ? x0 + 4 : 63;
    for (int ic = 0; ic < CIN; ++ic) {
        const float* p = inb + ic * 4096;
        float4 q0 = *(const float4*)(p + rm + x0);
        float4 q1 = *(const float4*)(p + r0 + x0);
        float4 q2 = *(const float4*)(p + rp + x0);
        float t0[6], t1[6], t2[6];
        t0[0] = selz(ym && xm, p[rm + cxm]);
        t0[1] = selz(ym, q0.x); t0[2] = selz(ym, q0.y);
        t0[3] = selz(ym, q0.z); t0[4] = selz(ym, q0.w);
        t0[5] = selz(ym && xp, p[rm + cxp]);
        t1[0] = selz(xm, p[r0 + cxm]);
        t1[1] = q1.x; t1[2] = q1.y; t1[3] = q1.z; t1[4] = q1.w;
        t1[5] = selz(xp, p[r0 + cxp]);
        t2[0] = selz(yp && xm, p[rp + cxm]);
        t2[1] = selz(yp, q2.x); t2[2] = selz(yp, q2.y);
        t2[3] = selz(yp, q2.z); t2[4] = selz(yp, q2.w);
        t2[5] = selz(yp && xp, p[rp + cxp]);
        #pragma unroll
        for (int o = 0; o < OCG; ++o) {
            const float* wr = W + (o * CIN + ic) * 9;
            #pragma unroll
            for (int px = 0; px < 4; ++px) {
                float a = acc[o][px];
                a = fmaf(t0[px], wr[0], a); a = fmaf(t0[px+1], wr[1], a); a = fmaf(t0[px+2], wr[2], a);
                a = fmaf(t1[px], wr[3], a); a = fmaf(t1[px+1], wr[4], a); a = fmaf(t1[px+2], wr[5], a);
                a = fmaf(t2[px], wr[6], a); a = fmaf(t2[px+1], wr[7], a); a = fmaf(t2[px+2], wr[8], a);
                acc[o][px] = a;
            }
        }
    }
    float* out = g_ws + out_off + ((size_t)b * Cout + g * OCG) * 4096 + y * 64 + x0;
    #pragma unroll
    for (int o = 0; o < OCG; ++o) {
        float4 v;
        if (relu) {
            v.x = fmaxf(acc[o][0], 0.f); v.y = fmaxf(acc[o][1], 0.f);
            v.z = fmaxf(acc[o][2], 0.f); v.w = fmaxf(acc[o][3], 0.f);
        } else {
            v.x = acc[o][0]; v.y = acc[o][1]; v.z = acc[o][2]; v.w = acc[o][3];
        }
        *(float4*)(out + o * 4096) = v;
    }
}

// ---------------- fused spatial softmax + moments; optionally write probs back ----------------
__global__ void sm_mom_k(int p_off, int mu_off, int linv_off, int write_p) {
    int bk = blockIdx.x;
    float* row = g_ws + p_off + (size_t)bk * 4096;
    float m = -1e30f;
    for (int i = threadIdx.x; i < 4096; i += 256) m = fmaxf(m, row[i]);
    m = block_max(m);
    float s = 0.f;
    for (int i = threadIdx.x; i < 4096; i += 256) s += __expf(row[i] - m);
    s = block_sum(s);
    float inv = 1.0f / s;
    float sy = 0, sx = 0, syy = 0, sxy = 0, sxx = 0;
    for (int i = threadIdx.x; i < 4096; i += 256) {
        float pv = __expf(row[i] - m) * inv;
        if (write_p) row[i] = pv;
        float gy = -1.0f + (i >> 6) * (2.0f / 63.0f);
        float gx = -1.0f + (i & 63) * (2.0f / 63.0f);
        sy += pv * gy; sx += pv * gx;
        syy += pv * gy * gy; sxy += pv * gy * gx; sxx += pv * gx * gx;
    }
    sy = block_sum(sy); sx = block_sum(sx);
    syy = block_sum(syy); sxy = block_sum(sxy); sxx = block_sum(sxx);
    if (threadIdx.x == 0) {
        float c00 = syy - sy * sy, c01 = sxy - sy * sx, c11 = sxx - sx * sx;
        float a = sqrtf(fmaxf(c00 + EPS, 1e-12f));
        float bb = c01 / (a + EPS);
        float cc = sqrtf(fmaxf(c11 - bb * bb, 0.f) + EPS);
        float det = a * cc;
        float sc = SCAL / (det + EPS);
        g_ws[mu_off + bk * 2 + 0] = sy;
        g_ws[mu_off + bk * 2 + 1] = sx;
        g_ws[linv_off + bk * 4 + 0] = cc * sc;
        g_ws[linv_off + bk * 4 + 1] = 0.f;
        g_ws[linv_off + bk * 4 + 2] = -bb * sc;
        g_ws[linv_off + bk * 4 + 3] = a * sc;
    }
}

// ---------------- alpha[b,k,f] = sum_hw fxs[b,f,hw] * parts[b,k,hw] ----------------
__global__ void alpha_k(int fxs_off, int parts_off) {
    int bk = blockIdx.x;
    int b = bk >> 4;
    float* alpha = g_ws + OFF_ALPHA;
    __shared__ float pl[4096];
    const float* pr = g_ws + parts_off + (size_t)bk * 4096;
    for (int i = threadIdx.x; i < 4096; i += 256) pl[i] = pr[i];
    __syncthreads();
    const float* fb = g_ws + fxs_off + (size_t)b * 32 * 4096;
    for (int f = 0; f < 32; ++f) {
        const float* fr = fb + f * 4096;
        float s = 0.f;
        for (int i = threadIdx.x; i < 4096; i += 256) s += fr[i] * pl[i];
        s = block_sum(s);
        if (threadIdx.x == 0) alpha[bk * 32 + f] = s;
    }
}

// ---------------- heat into enc ch[0..16), plus per-(b,k) sums ----------------
__global__ void heat_k(int mu_off, int linv_off, int enc_off) {
    int bk = blockIdx.x;
    int b = bk >> 4, k = bk & 15;
    float m0 = g_ws[mu_off + bk * 2], m1 = g_ws[mu_off + bk * 2 + 1];
    float L00 = g_ws[linv_off + bk * 4 + 0], L10 = g_ws[linv_off + bk * 4 + 2],
          L11 = g_ws[linv_off + bk * 4 + 3];
    float* out = g_ws + enc_off + ((size_t)b * 48 + k) * 4096;
    float s = 0.f;
    for (int i = threadIdx.x; i < 4096; i += 256) {
        float d0 = -1.0f + (i >> 6) * (2.0f / 63.0f) - m0;
        float d1 = -1.0f + (i & 63) * (2.0f / 63.0f) - m1;
        float p0 = d0 * L00 + d1 * L10;
        float p1 = d1 * L11;
        float h = 1.0f / (1.0f + p0 * p0 + p1 * p1);
        out[i] = h;
        s += h;
    }
    s = block_sum(s);
    if (threadIdx.x == 0) g_ws[OFF_HSUM + bk] = s;
}

// ---------------- fmap into enc ch[16..48) ----------------
__global__ void fmap_k(int enc_off) {
    int t = blockIdx.x;
    int tile = t & 15, bfi = t >> 4;
    int f = bfi & 31, b = bfi >> 5;
    __shared__ float coef[16];
    if (threadIdx.x < 16) {
        int k = threadIdx.x;
        coef[k] = g_ws[OFF_ALPHA + (b * 16 + k) * 32 + f] /
                  (g_ws[OFF_HSUM + b * 16 + k] + EPS);
    }
    __syncthreads();
    int pix = tile * 256 + threadIdx.x;
    const float* hb = g_ws + enc_off + (size_t)b * 48 * 4096 + pix;
    float acc = 0.f;
    for (int k = 0; k < 16; ++k) acc += hb[k * 4096] * coef[k];
    g_ws[enc_off + ((size_t)b * 48 + 16 + f) * 4096 + pix] = acc;
}

// ---------------- tiled decoder conv2 + fused 2x nearest upsample ----------------
// in fp32 [B,64,64,64] (read upsampled), out fp32 [B,32,128,128], relu
// grid: 32b * 2g * 16by; block 256 = 8 rows x 32 xq (x0 = 4*xq)
__global__ void conv_upmt_k(int in_off, int out_off) {
    int by = blockIdx.x & 15;
    int gb = blockIdx.x >> 4;
    int g = gb & 1, b = gb >> 1;
    int xq = threadIdx.x & 31, ry = threadIdx.x >> 5;
    int y = by * 8 + ry, x0 = xq * 4;
    const float* inb = g_ws + in_off + (size_t)b * 64 * 4096;
    const float* W = g_ws + W_DW2 + (size_t)(g * 16) * 576;
    float acc[16][4];
    #pragma unroll
    for (int o = 0; o < 16; ++o) {
        float bv = g_ws[W_DB2 + g * 16 + o];
        #pragma unroll
        for (int p = 0; p < 4; ++p) acc[o][p] = bv;
    }
    // cols: ux in {x0-1..x0+4} -> input cols {m-1,m,m,m+1,m+1,m+2}, m = x0/2
    int m = x0 >> 1;
    bool vxm = x0 > 0, vxp = x0 < 124;
    int c0 = vxm ? m - 1 : 0, c1 = m, c2 = m + 1, c3 = vxp ? m + 2 : 63;
    // rows: uy = y-1, y, y+1 -> input rows clamp(uy)/2
    bool yv0 = y > 0, yv2 = y < 127;
    int r0 = ((yv0 ? y - 1 : 0) >> 1) * 64;
    int r1 = (y >> 1) * 64;
    int r2 = ((yv2 ? y + 1 : 127) >> 1) * 64;
    for (int ic = 0; ic < 64; ++ic) {
        const float* p = inb + ic * 4096;
        float t0[6], t1[6], t2[6];
        {
            float L0 = p[r0 + c0], L1 = p[r0 + c1], L2 = p[r0 + c2], L3 = p[r0 + c3];
            t0[0] = selz(yv0 && vxm, L0);
            t0[1] = selz(yv0, L1); t0[2] = t0[1];
            t0[3] = selz(yv0, L2); t0[4] = t0[3];
            t0[5] = selz(yv0 && vxp, L3);
        }
        {
            float L0 = p[r1 + c0], L1 = p[r1 + c1], L2 = p[r1 + c2], L3 = p[r1 + c3];
            t1[0] = selz(vxm, L0);
            t1[1] = L1; t1[2] = L1;
            t1[3] = L2; t1[4] = L2;
            t1[5] = selz(vxp, L3);
        }
        {
            float L0 = p[r2 + c0], L1 = p[r2 + c1], L2 = p[r2 + c2], L3 = p[r2 + c3];
            t2[0] = selz(yv2 && vxm, L0);
            t2[1] = selz(yv2, L1); t2[2] = t2[1];
            t2[3] = selz(yv2, L2); t2[4] = t2[3];
            t2[5] = selz(yv2 && vxp, L3);
        }
        #pragma unroll
        for (int o = 0; o < 16; ++o) {
            const float* wr = W + (o * 64 + ic) * 9;
            #pragma unroll
            for (int px = 0; px < 4; ++px) {
                float a = acc[o][px];
                a = fmaf(t0[px], wr[0], a); a = fmaf(t0[px+1], wr[1], a); a = fmaf(t0[px+2], wr[2], a);
                a = fmaf(t1[px], wr[3], a); a = fmaf(t1[px+1], wr[4], a); a = fmaf(t1[px+2], wr[5], a);
                a = fmaf(t2[px], wr[6], a); a = fmaf(t2[px+1], wr[7], a); a = fmaf(t2[px+2], wr[8], a);
                acc[o][px] = a;
            }
        }
    }
    float* out = g_ws + out_off + ((size_t)b * 32 + g * 16) * 16384 + y * 128 + x0;
    #pragma unroll
    for (int o = 0; o < 16; ++o) {
        float4 v;
        v.x = fmaxf(acc[o][0], 0.f); v.y = fmaxf(acc[o][1], 0.f);
        v.z = fmaxf(acc[o][2], 0.f); v.w = fmaxf(acc[o][3], 0.f);
        *(float4*)(out + o * 16384) = v;
    }
}

// ---------------- tiled final conv + sigmoid -> out, fused rec-loss ----------------
// grid: 32b * 16by; block 256 = 8 rows x 32 xq
__global__ void conv_sigmt_k(int in_off, const void* __restrict__ ximg,
                             void* __restrict__ outp) {
    int bf = g_isbf16;
    int by = blockIdx.x & 15;
    int b = blockIdx.x >> 4;
    int xq = threadIdx.x & 31, ry = threadIdx.x >> 5;
    int y = by * 8 + ry, x0 = xq * 4;
    const float* inb = g_ws + in_off + (size_t)b * 32 * 16384;
    const float* W = g_ws + W_DW3;
    float acc[3][4];
    #pragma unroll
    for (int o = 0; o < 3; ++o) {
        float bv = g_ws[W_DB3 + o];
        #pragma unroll
        for (int p = 0; p < 4; ++p) acc[o][p] = bv;
    }
    bool ym = y > 0, yp = y < 127, xm = x0 > 0, xp = x0 < 124;
    int rm = (ym ? y - 1 : 0) * 128, r0 = y * 128, rp = (yp ? y + 1 : 127) * 128;
    int cxm = xm ? x0 - 1 : 0, cxp = xp ? x0 + 4 : 127;
    for (int ic = 0; ic < 32; ++ic) {
        const float* p = inb + ic * 16384;
        float4 q0 = *(const float4*)(p + rm + x0);
        float4 q1 = *(const float4*)(p + r0 + x0);
        float4 q2 = *(const float4*)(p + rp + x0);
        float t0[6], t1[6], t2[6];
        t0[0] = selz(ym && xm, p[rm + cxm]);
        t0[1] = selz(ym, q0.x); t0[2] = selz(ym, q0.y);
        t0[3] = selz(ym, q0.z); t0[4] = selz(ym, q0.w);
        t0[5] = selz(ym && xp, p[rm + cxp]);
        t1[0] = selz(xm, p[r0 + cxm]);
        t1[1] = q1.x; t1[2] = q1.y; t1[3] = q1.z; t1[4] = q1.w;
        t1[5] = selz(xp, p[r0 + cxp]);
        t2[0] = selz(yp && xm, p[rp + cxm]);
        t2[1] = selz(yp, q2.x); t2[2] = selz(yp, q2.y);
        t2[3] = selz(yp, q2.z); t2[4] = selz(yp, q2.w);
        t2[5] = selz(yp && xp, p[rp + cxp]);
        #pragma unroll
        for (int o = 0; o < 3; ++o) {
            const float* wr = W + (o * 32 + ic) * 9;
            #pragma unroll
            for (int px = 0; px < 4; ++px) {
                float a = acc[o][px];
                a = fmaf(t0[px], wr[0], a); a = fmaf(t0[px+1], wr[1], a); a = fmaf(t0[px+2], wr[2], a);
                a = fmaf(t1[px], wr[3], a); a = fmaf(t1[px+1], wr[4], a); a = fmaf(t1[px+2], wr[5], a);
                a = fmaf(t2[px], wr[6], a); a = fmaf(t2[px+1], wr[7], a); a = fmaf(t2[px+2], wr[8], a);
                acc[o][px] = a;
            }
        }
    }
    float es = 0.f;
    #pragma unroll
    for (int o = 0; o < 3; ++o) {
        #pragma unroll
        for (int px = 0; px < 4; ++px) {
            float v = 1.0f / (1.0f + __expf(-acc[o][px]));
            size_t oidx = ((size_t)b * 3 + o) * 16384 + y * 128 + x0 + px;
            if (bf) ((__hip_bfloat16*)outp)[oidx] = __float2bfloat16(v);
            else    ((float*)outp)[oidx] = v;
            float e = ldin(ximg, oidx, bf) - v;
            es += e * e;
        }
    }
    float s = block_sum(es);
    if (threadIdx.x == 0) atomicAdd(&g_ws[OFF_REC], s);
}

// ---------------- scalar loss ----------------
__global__ void loss_k(const void* __restrict__ coord,
                       const void* __restrict__ vec,
                       void* __restrict__ outp) {
    int bf = g_isbf16;
    const float* mu = g_ws + OFF_MU;
    const float* linv = g_ws + OFF_LINV;
    const float* mu_a = g_ws + OFF_MUA;
    const float* linv_a = g_ws + OFF_LINVA;
    float s1 = 0, s2 = 0, s3 = 0;
    for (int i = threadIdx.x; i < 1024; i += 256) {
        float d = mu[i] - mu_a[i];
        s1 += d * d;
        float t = ldin(coord, i, bf) + ldin(vec, i, bf);
        float d3 = mu_a[i] - t;
        s3 += d3 * d3;
    }
    for (int i = threadIdx.x; i < 2048; i += 256) {
        float d = linv[i] - linv_a[i];
        s2 += d * d;
    }
    s1 = block_sum(s1);
    s2 = block_sum(s2);
    s3 = block_sum(s3);
    if (threadIdx.x == 0) {
        float loss = g_ws[OFF_REC] / 1572864.0f + s1 / 1024.0f + 0.01f * (s2 / 2048.0f)
                   + s3 / 1024.0f;
        if (bf) ((__hip_bfloat16*)outp)[1572864] = __float2bfloat16(loss);
        else    ((float*)outp)[1572864] = loss;
    }
}

extern "C" void kernel_launch(void* const* d_in, const int* in_sizes, int n_in,
                              void* d_out, int out_size, void* d_ws, size_t ws_size,
                              hipStream_t stream) {
    const void* x     = d_in[0];
    const void* x_st  = d_in[1];
    const void* x_at  = d_in[2];
    const void* coord = d_in[3];
    const void* vec   = d_in[4];

    dim3 blk(256);

    detect_k<<<1, 64, 0, stream>>>(x);
    wconv_k<<<64, blk, 0, stream>>>(
        d_in[5],  d_in[6],  d_in[7],  d_in[8],
        d_in[9],  d_in[10], d_in[11], d_in[12],
        d_in[13], d_in[14], d_in[15], d_in[16],
        d_in[17], d_in[18], d_in[19], d_in[20]);

    // ---- shape stream: e_sigma(x_appearance_transform) -> mu, L_inv ----
    conv_s2m_k<<<32 * 4 * 16, blk, 0, stream>>>(x_at, OFF_R1);
    conv64t_k<64, 16><<<32 * 4 * 4, blk, 0, stream>>>(OFF_R1, W_ESW2, W_ESB2, OFF_R2, 4, 64, 1);
    conv64t_k<64, 16><<<32 * 1 * 4, blk, 0, stream>>>(OFF_R2, W_ESWP, W_ESBP, OFF_P, 1, 16, 0);
    sm_mom_k<<<512, blk, 0, stream>>>(OFF_P, OFF_MU, OFF_LINV, 0);

    // ---- appearance stream -> app_parts (P), app_sum (R2) ----
    conv_s2m_k<<<32 * 4 * 16, blk, 0, stream>>>(x_st, OFF_R1);
    conv64t_k<64, 16><<<32 * 4 * 4, blk, 0, stream>>>(OFF_R1, W_ESW2, W_ESB2, OFF_R2, 4, 64, 1);
    conv64t_k<64, 16><<<32 * 1 * 4, blk, 0, stream>>>(OFF_R2, W_ESWP, W_ESBP, OFF_P, 1, 16, 0);
    sm_mom_k<<<512, blk, 0, stream>>>(OFF_P, OFF_MUA, OFF_LINVA, 1);

    // ---- e_alpha(app_sum=R2) -> f_xs (C), then alpha ----
    conv64t_k<64, 16><<<32 * 4 * 4, blk, 0, stream>>>(OFF_R2, W_EAW1, W_EAB1, OFF_R1, 4, 64, 1);
    conv64t_k<64, 16><<<32 * 2 * 4, blk, 0, stream>>>(OFF_R1, W_EAW2, W_EAB2, OFF_C, 2, 32, 0);
    alpha_k<<<512, blk, 0, stream>>>(OFF_C, OFF_P);

    // ---- encoding into R1: heat (ch 0..15) + fmap (ch 16..47) ----
    heat_k<<<512, blk, 0, stream>>>(OFF_MU, OFF_LINV, OFF_R1);
    fmap_k<<<32 * 32 * 16, blk, 0, stream>>>(OFF_R1);

    // ---- decoder: E(R1) -> R2 -> R3 -> out ----
    conv64t_k<48, 16><<<32 * 4 * 4, blk, 0, stream>>>(OFF_R1, W_DW1, W_DB1, OFF_R2, 4, 64, 1);
    conv_upmt_k<<<32 * 2 * 16, blk, 0, stream>>>(OFF_R2, OFF_R3);   // P,C dead now
    conv_sigmt_k<<<32 * 16, blk, 0, stream>>>(OFF_R3, x, d_out);

    // ---- loss ----
    loss_k<<<1, blk, 0, stream>>>(coord, vec, d_out);
}

// Round 10
// 1411.971 us; speedup vs baseline: 6.3902x; 1.6300x over previous
//
#include <hip/hip_runtime.h>
#include <hip/hip_bf16.h>

#define EPS 1e-6f
#define SCAL 5.0f

// ---- static device scratch (zero-init BSS, graph-capture safe) ----
#define OFF_MU     0
#define OFF_LINV   1024
#define OFF_MUA    3072
#define OFF_LINVA  4096
#define OFF_HSUM   6144
#define OFF_ALPHA  6656
#define OFF_REC    23040
#define OFF_W      32768
#define OFF_R1     (OFF_W + 262144)
#define OFF_R2     (OFF_R1 + 8388608)
#define OFF_R3     (OFF_R2 + 8388608)
#define WS_TOTAL   (OFF_R3 + 16777216)

// B=64 batched staging (both streams; lifetimes verified):
//   X1 (conv1 out, [64,64,64,64])  -> R3            (dead after X2)
//   X2 (conv2 out, [64,64,64,64])  -> R1..R2 (16.8M); b 0-31 shape-h2, 32-63 app-h2
//   PARTS [64,16,64,64] (4.2M)     -> R3 front      (X1 dead)
//   C = f_xs [32,32,64,64] (4.2M)  -> R3 + 4.2M
//   E [32,48,64,64]                -> R1            (h1a dead)
//   D1 [32,64,64,64]               -> R2            (app-h2 dead)
//   D2 [32,32,128,128] (16.8M)     -> R3            (parts+C dead)
#define OFF_X1     OFF_R3
#define OFF_X2     OFF_R1
#define OFF_APPH2  OFF_R2
#define OFF_PARTS  OFF_R3
#define OFF_PARTSA (OFF_R3 + 2097152)
#define OFF_C2     (OFF_R3 + 4194304)

// fp32 weight/bias offsets inside OFF_W (filled by wconv_k)
#define W_ESW1 (OFF_W + 0)
#define W_ESB1 (OFF_W + 1728)
#define W_ESW2 (OFF_W + 1792)
#define W_ESB2 (OFF_W + 38656)
#define W_ESWP (OFF_W + 38720)
#define W_ESBP (OFF_W + 47936)
#define W_EAW1 (OFF_W + 47952)
#define W_EAB1 (OFF_W + 84816)
#define W_EAW2 (OFF_W + 84880)
#define W_EAB2 (OFF_W + 103312)
#define W_DW1  (OFF_W + 103344)
#define W_DB1  (OFF_W + 130992)
#define W_DW2  (OFF_W + 131056)
#define W_DB2  (OFF_W + 149488)
#define W_DW3  (OFF_W + 149520)
#define W_DB3  (OFF_W + 150384)

__device__ __attribute__((aligned(16))) float g_ws[WS_TOTAL];
__device__ int g_isbf16;

__device__ __forceinline__ float selz(bool c, float v) { return c ? v : 0.f; }

// runtime-dtype external load (adaptive pattern — required: fixed-dtype builds NaN'd)
__device__ __forceinline__ float ldin(const void* p, size_t i, int bf) {
    return bf ? __bfloat162float(((const __hip_bfloat16*)p)[i])
              : ((const float*)p)[i];
}

// ---------------- block reductions (blockDim.x == 256) ----------------
__device__ __forceinline__ float block_sum(float v) {
    __shared__ float sb[8];
    for (int off = 32; off; off >>= 1) v += __shfl_down(v, off, 64);
    int lane = threadIdx.x & 63, wid = threadIdx.x >> 6;
    __syncthreads();
    if (lane == 0) sb[wid] = v;
    __syncthreads();
    float r = 0.f;
    for (int i = 0; i < 4; ++i) r += sb[i];
    return r;
}

__device__ __forceinline__ float block_max(float v) {
    __shared__ float sb[8];
    for (int off = 32; off; off >>= 1) v = fmaxf(v, __shfl_down(v, off, 64));
    int lane = threadIdx.x & 63, wid = threadIdx.x >> 6;
    __syncthreads();
    if (lane == 0) sb[wid] = v;
    __syncthreads();
    float r = -1e30f;
    for (int i = 0; i < 4; ++i) r = fmaxf(r, sb[i]);
    return r;
}

// ---------------- dtype probe + init ----------------
__global__ void detect_k(const void* x) {
    const __hip_bfloat16* p = (const __hip_bfloat16*)x;
    int lane = threadIdx.x & 63;
    float v = 0.f;
    for (int i = lane; i < 256; i += 64) {
        float a = fabsf(__bfloat162float(p[i]));
        if (!(a <= 2.0f)) v = 1.f;          // catches big AND NaN
    }
    for (int off = 32; off; off >>= 1) v += __shfl_down(v, off, 64);
    if (lane == 0) {
        g_isbf16 = (v == 0.f) ? 1 : 0;
        g_ws[OFF_REC] = 0.f;
    }
}

// ---------------- weight prep: external dtype -> fp32 into g_ws[OFF_W..] ----------------
__global__ void wconv_k(const void* p0, const void* p1, const void* p2, const void* p3,
                        const void* p4, const void* p5, const void* p6, const void* p7,
                        const void* p8, const void* p9, const void* p10, const void* p11,
                        const void* p12, const void* p13, const void* p14, const void* p15) {
    int bf = g_isbf16;
    const void* ps[16] = {p0,p1,p2,p3,p4,p5,p6,p7,p8,p9,p10,p11,p12,p13,p14,p15};
    const int sz[16] = {1728,64,36864,64,9216,16,36864,64,18432,32,27648,64,18432,32,864,3};
    int gid = blockIdx.x * 256 + threadIdx.x, stride = gridDim.x * 256;
    int off = 0;
    for (int a = 0; a < 16; ++a) {
        const void* p = ps[a];
        for (int i = gid; i < sz[a]; i += stride)
            g_ws[OFF_W + off + i] = ldin(p, i, bf);
        off += sz[a];
    }
}

// ---------------- conv1 both streams: stride-2 -> fp32 [64,64,64,64], relu ----
// grid: 64b * 4g * 16 tiles; b<32 -> inA(x_at) batch b, else inB(x_st) batch b-32
__global__ void conv_s2m2_k(const void* __restrict__ inA, const void* __restrict__ inB,
                            int out_off) {
    int bf = g_isbf16;
    int tile = blockIdx.x & 15;
    int gb = blockIdx.x >> 4;
    int g = gb & 3, b = gb >> 2;
    const void* in = (b < 32) ? inA : inB;
    int bb = b & 31;
    int pix = tile * 256 + threadIdx.x;
    int y = pix >> 6, x = pix & 63;
    size_t inb = (size_t)bb * 3 * 16384;
    const float* W = g_ws + W_ESW1 + (size_t)(g * 16) * 27;
    float acc[16];
    #pragma unroll
    for (int o = 0; o < 16; ++o) acc[o] = g_ws[W_ESB1 + g * 16 + o];
    int iy0 = 2 * y, ix0 = 2 * x;
    bool my2 = (iy0 + 2 < 128), mx2 = (ix0 + 2 < 128);
    int iy2 = my2 ? iy0 + 2 : 127, ix2 = mx2 ? ix0 + 2 : 127;
    for (int ic = 0; ic < 3; ++ic) {
        size_t pb = inb + ic * 16384;
        float t[9];
        t[0] = ldin(in, pb + iy0 * 128 + ix0, bf);
        t[1] = ldin(in, pb + iy0 * 128 + ix0 + 1, bf);
        t[2] = selz(mx2, ldin(in, pb + iy0 * 128 + ix2, bf));
        t[3] = ldin(in, pb + (iy0 + 1) * 128 + ix0, bf);
        t[4] = ldin(in, pb + (iy0 + 1) * 128 + ix0 + 1, bf);
        t[5] = selz(mx2, ldin(in, pb + (iy0 + 1) * 128 + ix2, bf));
        t[6] = selz(my2, ldin(in, pb + iy2 * 128 + ix0, bf));
        t[7] = selz(my2, ldin(in, pb + iy2 * 128 + ix0 + 1, bf));
        t[8] = selz(my2 && mx2, ldin(in, pb + iy2 * 128 + ix2, bf));
        #pragma unroll
        for (int o = 0; o < 16; ++o) {
            const float* wr = W + (o * 3 + ic) * 9;
            float a = acc[o];
            #pragma unroll
            for (int j = 0; j < 9; ++j) a = fmaf(t[j], wr[j], a);
            acc[o] = a;
        }
    }
    float* out = g_ws + out_off + ((size_t)b * 64 + g * 16) * 4096 + pix;
    #pragma unroll
    for (int o = 0; o < 16; ++o) out[o * 4096] = fmaxf(acc[o], 0.f);
}

// ---------------- tiled 3x3 SAME conv on 64x64 planes: 1x4 px x OCG ocs per thread ----
// grid: B * ng * 4by; block 256 = 16 rows x 16 xq
template<int CIN, int OCG>
__global__ void conv64t_k(int in_off, int w_off, int b_off, int out_off,
                          int ng, int Cout, int relu) {
    int by = blockIdx.x & 3;
    int gb = blockIdx.x >> 2;
    int g = gb % ng, b = gb / ng;
    int xq = threadIdx.x & 15, ry = threadIdx.x >> 4;
    int y = by * 16 + ry, x0 = xq * 4;
    const float* inb = g_ws + in_off + (size_t)b * CIN * 4096;
    const float* W = g_ws + w_off + (size_t)(g * OCG) * CIN * 9;
    float acc[OCG][4];
    #pragma unroll
    for (int o = 0; o < OCG; ++o) {
        float bv = g_ws[b_off + g * OCG + o];
        #pragma unroll
        for (int p = 0; p < 4; ++p) acc[o][p] = bv;
    }
    bool ym = y > 0, yp = y < 63, xm = x0 > 0, xp = x0 < 60;
    int rm = (ym ? y - 1 : 0) * 64, r0 = y * 64, rp = (yp ? y + 1 : 63) * 64;
    int cxm = xm ? x0 - 1 : 0, cxp = xp ? x0 + 4 : 63;
    for (int ic = 0; ic < CIN; ++ic) {
        const float* p = inb + ic * 4096;
        float4 q0 = *(const float4*)(p + rm + x0);
        float4 q1 = *(const float4*)(p + r0 + x0);
        float4 q2 = *(const float4*)(p + rp + x0);
        float t0[6], t1[6], t2[6];
        t0[0] = selz(ym && xm, p[rm + cxm]);
        t0[1] = selz(ym, q0.x); t0[2] = selz(ym, q0.y);
        t0[3] = selz(ym, q0.z); t0[4] = selz(ym, q0.w);
        t0[5] = selz(ym && xp, p[rm + cxp]);
        t1[0] = selz(xm, p[r0 + cxm]);
        t1[1] = q1.x; t1[2] = q1.y; t1[3] = q1.z; t1[4] = q1.w;
        t1[5] = selz(xp, p[r0 + cxp]);
        t2[0] = selz(yp && xm, p[rp + cxm]);
        t2[1] = selz(yp, q2.x); t2[2] = selz(yp, q2.y);
        t2[3] = selz(yp, q2.z); t2[4] = selz(yp, q2.w);
        t2[5] = selz(yp && xp, p[rp + cxp]);
        #pragma unroll
        for (int o = 0; o < OCG; ++o) {
            const float* wr = W + (o * CIN + ic) * 9;
            #pragma unroll
            for (int px = 0; px < 4; ++px) {
                float a = acc[o][px];
                a = fmaf(t0[px], wr[0], a); a = fmaf(t0[px+1], wr[1], a); a = fmaf(t0[px+2], wr[2], a);
                a = fmaf(t1[px], wr[3], a); a = fmaf(t1[px+1], wr[4], a); a = fmaf(t1[px+2], wr[5], a);
                a = fmaf(t2[px], wr[6], a); a = fmaf(t2[px+1], wr[7], a); a = fmaf(t2[px+2], wr[8], a);
                acc[o][px] = a;
            }
        }
    }
    float* out = g_ws + out_off + ((size_t)b * Cout + g * OCG) * 4096 + y * 64 + x0;
    #pragma unroll
    for (int o = 0; o < OCG; ++o) {
        float4 v;
        if (relu) {
            v.x = fmaxf(acc[o][0], 0.f); v.y = fmaxf(acc[o][1], 0.f);
            v.z = fmaxf(acc[o][2], 0.f); v.w = fmaxf(acc[o][3], 0.f);
        } else {
            v.x = acc[o][0]; v.y = acc[o][1]; v.z = acc[o][2]; v.w = acc[o][3];
        }
        *(float4*)(out + o * 4096) = v;
    }
}

// ---------------- fused softmax+moments over all 1024 (b,k) rows ----------------
// rows 0..511 = shape -> mu/linv; rows 512..1023 = app -> mu_a/linv_a + write probs
__global__ void sm_mom2_k() {
    int bk = blockIdx.x;
    int app = (bk >= 512);
    float* row = g_ws + OFF_PARTS + (size_t)bk * 4096;
    float r[16];
    #pragma unroll
    for (int j = 0; j < 16; ++j) r[j] = row[threadIdx.x + j * 256];
    float m = r[0];
    #pragma unroll
    for (int j = 1; j < 16; ++j) m = fmaxf(m, r[j]);
    m = block_max(m);
    float s = 0.f;
    #pragma unroll
    for (int j = 0; j < 16; ++j) { r[j] = __expf(r[j] - m); s += r[j]; }
    s = block_sum(s);
    float inv = 1.0f / s;
    float sy = 0, sx = 0, syy = 0, sxy = 0, sxx = 0;
    #pragma unroll
    for (int j = 0; j < 16; ++j) {
        float pv = r[j] * inv;
        int i = threadIdx.x + j * 256;
        if (app) row[i] = pv;
        float gy = -1.0f + (i >> 6) * (2.0f / 63.0f);
        float gx = -1.0f + (i & 63) * (2.0f / 63.0f);
        sy += pv * gy; sx += pv * gx;
        syy += pv * gy * gy; sxy += pv * gy * gx; sxx += pv * gx * gx;
    }
    sy = block_sum(sy); sx = block_sum(sx);
    syy = block_sum(syy); sxy = block_sum(sxy); sxx = block_sum(sxx);
    if (threadIdx.x == 0) {
        float c00 = syy - sy * sy, c01 = sxy - sy * sx, c11 = sxx - sx * sx;
        float a = sqrtf(fmaxf(c00 + EPS, 1e-12f));
        float bb = c01 / (a + EPS);
        float cc = sqrtf(fmaxf(c11 - bb * bb, 0.f) + EPS);
        float det = a * cc;
        float sc = SCAL / (det + EPS);
        int idx = app ? (bk - 512) : bk;
        int mu_off = app ? OFF_MUA : OFF_MU;
        int linv_off = app ? OFF_LINVA : OFF_LINV;
        g_ws[mu_off + idx * 2 + 0] = sy;
        g_ws[mu_off + idx * 2 + 1] = sx;
        g_ws[linv_off + idx * 4 + 0] = cc * sc;
        g_ws[linv_off + idx * 4 + 1] = 0.f;
        g_ws[linv_off + idx * 4 + 2] = -bb * sc;
        g_ws[linv_off + idx * 4 + 3] = a * sc;
    }
}

// ---------------- alpha[b,k,f] = sum_hw fxs[b,f,hw] * parts[b,k,hw] ----------------
__global__ void alpha_k(int fxs_off, int parts_off) {
    int bk = blockIdx.x;
    int b = bk >> 4;
    float* alpha = g_ws + OFF_ALPHA;
    __shared__ float pl[4096];
    const float* pr = g_ws + parts_off + (size_t)bk * 4096;
    for (int i = threadIdx.x; i < 4096; i += 256) pl[i] = pr[i];
    __syncthreads();
    const float* fb = g_ws + fxs_off + (size_t)b * 32 * 4096;
    for (int f = 0; f < 32; ++f) {
        const float* fr = fb + f * 4096;
        float s = 0.f;
        for (int i = threadIdx.x; i < 4096; i += 256) s += fr[i] * pl[i];
        s = block_sum(s);
        if (threadIdx.x == 0) alpha[bk * 32 + f] = s;
    }
}

// ---------------- heat into enc ch[0..16), plus per-(b,k) sums ----------------
__global__ void heat_k(int mu_off, int linv_off, int enc_off) {
    int bk = blockIdx.x;
    int b = bk >> 4, k = bk & 15;
    float m0 = g_ws[mu_off + bk * 2], m1 = g_ws[mu_off + bk * 2 + 1];
    float L00 = g_ws[linv_off + bk * 4 + 0], L10 = g_ws[linv_off + bk * 4 + 2],
          L11 = g_ws[linv_off + bk * 4 + 3];
    float* out = g_ws + enc_off + ((size_t)b * 48 + k) * 4096;
    float s = 0.f;
    for (int i = threadIdx.x; i < 4096; i += 256) {
        float d0 = -1.0f + (i >> 6) * (2.0f / 63.0f) - m0;
        float d1 = -1.0f + (i & 63) * (2.0f / 63.0f) - m1;
        float p0 = d0 * L00 + d1 * L10;
        float p1 = d1 * L11;
        float h = 1.0f / (1.0f + p0 * p0 + p1 * p1);
        out[i] = h;
        s += h;
    }
    s = block_sum(s);
    if (threadIdx.x == 0) g_ws[OFF_HSUM + bk] = s;
}

// ---------------- fmap into enc ch[16..48) ----------------
__global__ void fmap_k(int enc_off) {
    int t = blockIdx.x;
    int tile = t & 15, bfi = t >> 4;
    int f = bfi & 31, b = bfi >> 5;
    __shared__ float coef[16];
    if (threadIdx.x < 16) {
        int k = threadIdx.x;
        coef[k] = g_ws[OFF_ALPHA + (b * 16 + k) * 32 + f] /
                  (g_ws[OFF_HSUM + b * 16 + k] + EPS);
    }
    __syncthreads();
    int pix = tile * 256 + threadIdx.x;
    const float* hb = g_ws + enc_off + (size_t)b * 48 * 4096 + pix;
    float acc = 0.f;
    for (int k = 0; k < 16; ++k) acc += hb[k * 4096] * coef[k];
    g_ws[enc_off + ((size_t)b * 48 + 16 + f) * 4096 + pix] = acc;
}

// ---------------- tiled decoder conv2 + fused 2x nearest upsample ----------------
// grid: 32b * 2g * 16by; block 256 = 8 rows x 32 xq (x0 = 4*xq)
__global__ void conv_upmt_k(int in_off, int out_off) {
    int by = blockIdx.x & 15;
    int gb = blockIdx.x >> 4;
    int g = gb & 1, b = gb >> 1;
    int xq = threadIdx.x & 31, ry = threadIdx.x >> 5;
    int y = by * 8 + ry, x0 = xq * 4;
    const float* inb = g_ws + in_off + (size_t)b * 64 * 4096;
    const float* W = g_ws + W_DW2 + (size_t)(g * 16) * 576;
    float acc[16][4];
    #pragma unroll
    for (int o = 0; o < 16; ++o) {
        float bv = g_ws[W_DB2 + g * 16 + o];
        #pragma unroll
        for (int p = 0; p < 4; ++p) acc[o][p] = bv;
    }
    int m = x0 >> 1;
    bool vxm = x0 > 0, vxp = x0 < 124;
    int c0 = vxm ? m - 1 : 0, c1 = m, c2 = m + 1, c3 = vxp ? m + 2 : 63;
    bool yv0 = y > 0, yv2 = y < 127;
    int r0 = ((yv0 ? y - 1 : 0) >> 1) * 64;
    int r1 = (y >> 1) * 64;
    int r2 = ((yv2 ? y + 1 : 127) >> 1) * 64;
    for (int ic = 0; ic < 64; ++ic) {
        const float* p = inb + ic * 4096;
        float t0[6], t1[6], t2[6];
        {
            float L0 = p[r0 + c0], L1 = p[r0 + c1], L2 = p[r0 + c2], L3 = p[r0 + c3];
            t0[0] = selz(yv0 && vxm, L0);
            t0[1] = selz(yv0, L1); t0[2] = t0[1];
            t0[3] = selz(yv0, L2); t0[4] = t0[3];
            t0[5] = selz(yv0 && vxp, L3);
        }
        {
            float L0 = p[r1 + c0], L1 = p[r1 + c1], L2 = p[r1 + c2], L3 = p[r1 + c3];
            t1[0] = selz(vxm, L0);
            t1[1] = L1; t1[2] = L1;
            t1[3] = L2; t1[4] = L2;
            t1[5] = selz(vxp, L3);
        }
        {
            float L0 = p[r2 + c0], L1 = p[r2 + c1], L2 = p[r2 + c2], L3 = p[r2 + c3];
            t2[0] = selz(yv2 && vxm, L0);
            t2[1] = selz(yv2, L1); t2[2] = t2[1];
            t2[3] = selz(yv2, L2); t2[4] = t2[3];
            t2[5] = selz(yv2 && vxp, L3);
        }
        #pragma unroll
        for (int o = 0; o < 16; ++o) {
            const float* wr = W + (o * 64 + ic) * 9;
            #pragma unroll
            for (int px = 0; px < 4; ++px) {
                float a = acc[o][px];
                a = fmaf(t0[px], wr[0], a); a = fmaf(t0[px+1], wr[1], a); a = fmaf(t0[px+2], wr[2], a);
                a = fmaf(t1[px], wr[3], a); a = fmaf(t1[px+1], wr[4], a); a = fmaf(t1[px+2], wr[5], a);
                a = fmaf(t2[px], wr[6], a); a = fmaf(t2[px+1], wr[7], a); a = fmaf(t2[px+2], wr[8], a);
                acc[o][px] = a;
            }
        }
    }
    float* out = g_ws + out_off + ((size_t)b * 32 + g * 16) * 16384 + y * 128 + x0;
    #pragma unroll
    for (int o = 0; o < 16; ++o) {
        float4 v;
        v.x = fmaxf(acc[o][0], 0.f); v.y = fmaxf(acc[o][1], 0.f);
        v.z = fmaxf(acc[o][2], 0.f); v.w = fmaxf(acc[o][3], 0.f);
        *(float4*)(out + o * 16384) = v;
    }
}

// ---------------- tiled final conv + sigmoid -> out, fused rec-loss ----------------
// grid: 32b * 16by; block 256 = 8 rows x 32 xq
__global__ void conv_sigmt_k(int in_off, const void* __restrict__ ximg,
                             void* __restrict__ outp) {
    int bf = g_isbf16;
    int by = blockIdx.x & 15;
    int b = blockIdx.x >> 4;
    int xq = threadIdx.x & 31, ry = threadIdx.x >> 5;
    int y = by * 8 + ry, x0 = xq * 4;
    const float* inb = g_ws + in_off + (size_t)b * 32 * 16384;
    const float* W = g_ws + W_DW3;
    float acc[3][4];
    #pragma unroll
    for (int o = 0; o < 3; ++o) {
        float bv = g_ws[W_DB3 + o];
        #pragma unroll
        for (int p = 0; p < 4; ++p) acc[o][p] = bv;
    }
    bool ym = y > 0, yp = y < 127, xm = x0 > 0, xp = x0 < 124;
    int rm = (ym ? y - 1 : 0) * 128, r0 = y * 128, rp = (yp ? y + 1 : 127) * 128;
    int cxm = xm ? x0 - 1 : 0, cxp = xp ? x0 + 4 : 127;
    for (int ic = 0; ic < 32; ++ic) {
        const float* p = inb + ic * 16384;
        float4 q0 = *(const float4*)(p + rm + x0);
        float4 q1 = *(const float4*)(p + r0 + x0);
        float4 q2 = *(const float4*)(p + rp + x0);
        float t0[6], t1[6], t2[6];
        t0[0] = selz(ym && xm, p[rm + cxm]);
        t0[1] = selz(ym, q0.x); t0[2] = selz(ym, q0.y);
        t0[3] = selz(ym, q0.z); t0[4] = selz(ym, q0.w);
        t0[5] = selz(ym && xp, p[rm + cxp]);
        t1[0] = selz(xm, p[r0 + cxm]);
        t1[1] = q1.x; t1[2] = q1.y; t1[3] = q1.z; t1[4] = q1.w;
        t1[5] = selz(xp, p[r0 + cxp]);
        t2[0] = selz(yp && xm, p[rp + cxm]);
        t2[1] = selz(yp, q2.x); t2[2] = selz(yp, q2.y);
        t2[3] = selz(yp, q2.z); t2[4] = selz(yp, q2.w);
        t2[5] = selz(yp && xp, p[rp + cxp]);
        #pragma unroll
        for (int o = 0; o < 3; ++o) {
            const float* wr = W + (o * 32 + ic) * 9;
            #pragma unroll
            for (int px = 0; px < 4; ++px) {
                float a = acc[o][px];
                a = fmaf(t0[px], wr[0], a); a = fmaf(t0[px+1], wr[1], a); a = fmaf(t0[px+2], wr[2], a);
                a = fmaf(t1[px], wr[3], a); a = fmaf(t1[px+1], wr[4], a); a = fmaf(t1[px+2], wr[5], a);
                a = fmaf(t2[px], wr[6], a); a = fmaf(t2[px+1], wr[7], a); a = fmaf(t2[px+2], wr[8], a);
                acc[o][px] = a;
            }
        }
    }
    float es = 0.f;
    #pragma unroll
    for (int o = 0; o < 3; ++o) {
        #pragma unroll
        for (int px = 0; px < 4; ++px) {
            float v = 1.0f / (1.0f + __expf(-acc[o][px]));
            size_t oidx = ((size_t)b * 3 + o) * 16384 + y * 128 + x0 + px;
            if (bf) ((__hip_bfloat16*)outp)[oidx] = __float2bfloat16(v);
            else    ((float*)outp)[oidx] = v;
            float e = ldin(ximg, oidx, bf) - v;
            es += e * e;
        }
    }
    float s = block_sum(es);
    if (threadIdx.x == 0) atomicAdd(&g_ws[OFF_REC], s);
}

// ---------------- scalar loss ----------------
__global__ void loss_k(const void* __restrict__ coord,
                       const void* __restrict__ vec,
                       void* __restrict__ outp) {
    int bf = g_isbf16;
    const float* mu = g_ws + OFF_MU;
    const float* linv = g_ws + OFF_LINV;
    const float* mu_a = g_ws + OFF_MUA;
    const float* linv_a = g_ws + OFF_LINVA;
    float s1 = 0, s2 = 0, s3 = 0;
    for (int i = threadIdx.x; i < 1024; i += 256) {
        float d = mu[i] - mu_a[i];
        s1 += d * d;
        float t = ldin(coord, i, bf) + ldin(vec, i, bf);
        float d3 = mu_a[i] - t;
        s3 += d3 * d3;
    }
    for (int i = threadIdx.x; i < 2048; i += 256) {
        float d = linv[i] - linv_a[i];
        s2 += d * d;
    }
    s1 = block_sum(s1);
    s2 = block_sum(s2);
    s3 = block_sum(s3);
    if (threadIdx.x == 0) {
        float loss = g_ws[OFF_REC] / 1572864.0f + s1 / 1024.0f + 0.01f * (s2 / 2048.0f)
                   + s3 / 1024.0f;
        if (bf) ((__hip_bfloat16*)outp)[1572864] = __float2bfloat16(loss);
        else    ((float*)outp)[1572864] = loss;
    }
}

extern "C" void kernel_launch(void* const* d_in, const int* in_sizes, int n_in,
                              void* d_out, int out_size, void* d_ws, size_t ws_size,
                              hipStream_t stream) {
    const void* x     = d_in[0];
    const void* x_st  = d_in[1];
    const void* x_at  = d_in[2];
    const void* coord = d_in[3];
    const void* vec   = d_in[4];

    dim3 blk(256);

    detect_k<<<1, 64, 0, stream>>>(x);
    wconv_k<<<64, blk, 0, stream>>>(
        d_in[5],  d_in[6],  d_in[7],  d_in[8],
        d_in[9],  d_in[10], d_in[11], d_in[12],
        d_in[13], d_in[14], d_in[15], d_in[16],
        d_in[17], d_in[18], d_in[19], d_in[20]);

    // ---- both encoder streams batched (B=64): conv1 -> X1(R3), conv2 -> X2(R1R2) ----
    conv_s2m2_k<<<64 * 4 * 16, blk, 0, stream>>>(x_at, x_st, OFF_X1);
    conv64t_k<64, 16><<<64 * 4 * 4, blk, 0, stream>>>(OFF_X1, W_ESW2, W_ESB2, OFF_X2, 4, 64, 1);
    conv64t_k<64, 8><<<64 * 2 * 4, blk, 0, stream>>>(OFF_X2, W_ESWP, W_ESBP, OFF_PARTS, 2, 16, 0);
    sm_mom2_k<<<1024, blk, 0, stream>>>();

    // ---- e_alpha(app_sum = X2 batches 32..63 = R2) -> f_xs (C2), then alpha ----
    conv64t_k<64, 8><<<32 * 8 * 4, blk, 0, stream>>>(OFF_APPH2, W_EAW1, W_EAB1, OFF_R1, 8, 64, 1);
    conv64t_k<64, 8><<<32 * 4 * 4, blk, 0, stream>>>(OFF_R1, W_EAW2, W_EAB2, OFF_C2, 4, 32, 0);
    alpha_k<<<512, blk, 0, stream>>>(OFF_C2, OFF_PARTSA);

    // ---- encoding into R1: heat (ch 0..15, shape mu/linv) + fmap (ch 16..47) ----
    heat_k<<<512, blk, 0, stream>>>(OFF_MU, OFF_LINV, OFF_R1);
    fmap_k<<<32 * 32 * 16, blk, 0, stream>>>(OFF_R1);

    // ---- decoder: E(R1) -> D1(R2) -> D2(R3) -> out ----
    conv64t_k<48, 8><<<32 * 8 * 4, blk, 0, stream>>>(OFF_R1, W_DW1, W_DB1, OFF_R2, 8, 64, 1);
    conv_upmt_k<<<32 * 2 * 16, blk, 0, stream>>>(OFF_R2, OFF_R3);
    conv_sigmt_k<<<32 * 16, blk, 0, stream>>>(OFF_R3, x, d_out);

    // ---- loss ----
    loss_k<<<1, blk, 0, stream>>>(coord, vec, d_out);
}

// Round 11
// 1400.556 us; speedup vs baseline: 6.4423x; 1.0082x over previous
//
#include <hip/hip_runtime.h>
#include <hip/hip_bf16.h>

#define EPS 1e-6f
#define SCAL 5.0f

// ---- static device scratch (zero-init BSS, graph-capture safe) ----
#define OFF_MU     0
#define OFF_LINV   1024
#define OFF_MUA    3072
#define OFF_LINVA  4096
#define OFF_HSUM   6144
#define OFF_ALPHA  6656
#define OFF_REC    23040
#define OFF_W      32768
#define OFF_R1     (OFF_W + 262144)
#define OFF_R2     (OFF_R1 + 8388608)
#define OFF_R3     (OFF_R2 + 8388608)
#define WS_TOTAL   (OFF_R3 + 16777216)

// B=64 batched staging (both streams; lifetimes verified):
#define OFF_X1     OFF_R3
#define OFF_X2     OFF_R1
#define OFF_APPH2  OFF_R2
#define OFF_PARTS  OFF_R3
#define OFF_PARTSA (OFF_R3 + 2097152)
#define OFF_C2     (OFF_R3 + 4194304)

// fp32 weight/bias offsets inside OFF_W (filled by wconv_k)
#define W_ESW1 (OFF_W + 0)
#define W_ESB1 (OFF_W + 1728)
#define W_ESW2 (OFF_W + 1792)
#define W_ESB2 (OFF_W + 38656)
#define W_ESWP (OFF_W + 38720)
#define W_ESBP (OFF_W + 47936)
#define W_EAW1 (OFF_W + 47952)
#define W_EAB1 (OFF_W + 84816)
#define W_EAW2 (OFF_W + 84880)
#define W_EAB2 (OFF_W + 103312)
#define W_DW1  (OFF_W + 103344)
#define W_DB1  (OFF_W + 130992)
#define W_DW2  (OFF_W + 131056)
#define W_DB2  (OFF_W + 149488)
#define W_DW3  (OFF_W + 149520)
#define W_DB3  (OFF_W + 150384)

__device__ __attribute__((aligned(16))) float g_ws[WS_TOTAL];
__device__ int g_isbf16;

__device__ __forceinline__ float selz(bool c, float v) { return c ? v : 0.f; }

// runtime-dtype external load (adaptive pattern — required: fixed-dtype builds NaN'd)
__device__ __forceinline__ float ldin(const void* p, size_t i, int bf) {
    return bf ? __bfloat162float(((const __hip_bfloat16*)p)[i])
              : ((const float*)p)[i];
}

// ---------------- block reductions (blockDim.x == 256) ----------------
__device__ __forceinline__ float block_sum(float v) {
    __shared__ float sb[8];
    for (int off = 32; off; off >>= 1) v += __shfl_down(v, off, 64);
    int lane = threadIdx.x & 63, wid = threadIdx.x >> 6;
    __syncthreads();
    if (lane == 0) sb[wid] = v;
    __syncthreads();
    float r = 0.f;
    for (int i = 0; i < 4; ++i) r += sb[i];
    return r;
}

__device__ __forceinline__ float block_max(float v) {
    __shared__ float sb[8];
    for (int off = 32; off; off >>= 1) v = fmaxf(v, __shfl_down(v, off, 64));
    int lane = threadIdx.x & 63, wid = threadIdx.x >> 6;
    __syncthreads();
    if (lane == 0) sb[wid] = v;
    __syncthreads();
    float r = -1e30f;
    for (int i = 0; i < 4; ++i) r = fmaxf(r, sb[i]);
    return r;
}

// ---------------- dtype probe + init ----------------
__global__ void detect_k(const void* x) {
    const __hip_bfloat16* p = (const __hip_bfloat16*)x;
    int lane = threadIdx.x & 63;
    float v = 0.f;
    for (int i = lane; i < 256; i += 64) {
        float a = fabsf(__bfloat162float(p[i]));
        if (!(a <= 2.0f)) v = 1.f;          // catches big AND NaN
    }
    for (int off = 32; off; off >>= 1) v += __shfl_down(v, off, 64);
    if (lane == 0) {
        g_isbf16 = (v == 0.f) ? 1 : 0;
        g_ws[OFF_REC] = 0.f;
    }
}

// ---------------- weight prep: external dtype -> fp32 into g_ws[OFF_W..] ----------------
__global__ void wconv_k(const void* p0, const void* p1, const void* p2, const void* p3,
                        const void* p4, const void* p5, const void* p6, const void* p7,
                        const void* p8, const void* p9, const void* p10, const void* p11,
                        const void* p12, const void* p13, const void* p14, const void* p15) {
    int bf = g_isbf16;
    const void* ps[16] = {p0,p1,p2,p3,p4,p5,p6,p7,p8,p9,p10,p11,p12,p13,p14,p15};
    const int sz[16] = {1728,64,36864,64,9216,16,36864,64,18432,32,27648,64,18432,32,864,3};
    int gid = blockIdx.x * 256 + threadIdx.x, stride = gridDim.x * 256;
    int off = 0;
    for (int a = 0; a < 16; ++a) {
        const void* p = ps[a];
        for (int i = gid; i < sz[a]; i += stride)
            g_ws[OFF_W + off + i] = ldin(p, i, bf);
        off += sz[a];
    }
}

// ---------------- conv1 both streams: stride-2 -> fp32 [64,64,64,64], relu ----
__global__ void __launch_bounds__(256, 4)
conv_s2m2_k(const void* __restrict__ inA, const void* __restrict__ inB, int out_off) {
    int bf = g_isbf16;
    int tile = blockIdx.x & 15;
    int gb = blockIdx.x >> 4;
    int g = gb & 3, b = gb >> 2;
    const void* in = (b < 32) ? inA : inB;
    int bb = b & 31;
    int pix = tile * 256 + threadIdx.x;
    int y = pix >> 6, x = pix & 63;
    size_t inb = (size_t)bb * 3 * 16384;
    const float* W = g_ws + W_ESW1 + (size_t)(g * 16) * 27;
    float acc[16];
    #pragma unroll
    for (int o = 0; o < 16; ++o) acc[o] = g_ws[W_ESB1 + g * 16 + o];
    int iy0 = 2 * y, ix0 = 2 * x;
    bool my2 = (iy0 + 2 < 128), mx2 = (ix0 + 2 < 128);
    int iy2 = my2 ? iy0 + 2 : 127, ix2 = mx2 ? ix0 + 2 : 127;
    for (int ic = 0; ic < 3; ++ic) {
        size_t pb = inb + ic * 16384;
        float t[9];
        t[0] = ldin(in, pb + iy0 * 128 + ix0, bf);
        t[1] = ldin(in, pb + iy0 * 128 + ix0 + 1, bf);
        t[2] = selz(mx2, ldin(in, pb + iy0 * 128 + ix2, bf));
        t[3] = ldin(in, pb + (iy0 + 1) * 128 + ix0, bf);
        t[4] = ldin(in, pb + (iy0 + 1) * 128 + ix0 + 1, bf);
        t[5] = selz(mx2, ldin(in, pb + (iy0 + 1) * 128 + ix2, bf));
        t[6] = selz(my2, ldin(in, pb + iy2 * 128 + ix0, bf));
        t[7] = selz(my2, ldin(in, pb + iy2 * 128 + ix0 + 1, bf));
        t[8] = selz(my2 && mx2, ldin(in, pb + iy2 * 128 + ix2, bf));
        #pragma unroll
        for (int o = 0; o < 16; ++o) {
            const float* wr = W + (o * 3 + ic) * 9;
            float a = acc[o];
            #pragma unroll
            for (int j = 0; j < 9; ++j) a = fmaf(t[j], wr[j], a);
            acc[o] = a;
        }
    }
    float* out = g_ws + out_off + ((size_t)b * 64 + g * 16) * 4096 + pix;
    #pragma unroll
    for (int o = 0; o < 16; ++o) out[o * 4096] = fmaxf(acc[o], 0.f);
}

// ---------------- tiled 3x3 SAME conv on 64x64 planes: 1x4 px x OCG ocs per thread ----
// __launch_bounds__(256,4): VGPR cap 128 — acc[16][4]=64 + taps ~30 fits, NO SPILL
template<int CIN, int OCG>
__global__ void __launch_bounds__(256, 4)
conv64t_k(int in_off, int w_off, int b_off, int out_off, int ng, int Cout, int relu) {
    int by = blockIdx.x & 3;
    int gb = blockIdx.x >> 2;
    int g = gb % ng, b = gb / ng;
    int xq = threadIdx.x & 15, ry = threadIdx.x >> 4;
    int y = by * 16 + ry, x0 = xq * 4;
    const float* inb = g_ws + in_off + (size_t)b * CIN * 4096;
    const float* W = g_ws + w_off + (size_t)(g * OCG) * CIN * 9;
    float acc[OCG][4];
    #pragma unroll
    for (int o = 0; o < OCG; ++o) {
        float bv = g_ws[b_off + g * OCG + o];
        #pragma unroll
        for (int p = 0; p < 4; ++p) acc[o][p] = bv;
    }
    bool ym = y > 0, yp = y < 63, xm = x0 > 0, xp = x0 < 60;
    int rm = (ym ? y - 1 : 0) * 64, r0 = y * 64, rp = (yp ? y + 1 : 63) * 64;
    int cxm = xm ? x0 - 1 : 0, cxp = xp ? x0 + 4 : 63;
    for (int ic = 0; ic < CIN; ++ic) {
        const float* p = inb + ic * 4096;
        float4 q0 = *(const float4*)(p + rm + x0);
        float4 q1 = *(const float4*)(p + r0 + x0);
        float4 q2 = *(const float4*)(p + rp + x0);
        float t0[6], t1[6], t2[6];
        t0[0] = selz(ym && xm, p[rm + cxm]);
        t0[1] = selz(ym, q0.x); t0[2] = selz(ym, q0.y);
        t0[3] = selz(ym, q0.z); t0[4] = selz(ym, q0.w);
        t0[5] = selz(ym && xp, p[rm + cxp]);
        t1[0] = selz(xm, p[r0 + cxm]);
        t1[1] = q1.x; t1[2] = q1.y; t1[3] = q1.z; t1[4] = q1.w;
        t1[5] = selz(xp, p[r0 + cxp]);
        t2[0] = selz(yp && xm, p[rp + cxm]);
        t2[1] = selz(yp, q2.x); t2[2] = selz(yp, q2.y);
        t2[3] = selz(yp, q2.z); t2[4] = selz(yp, q2.w);
        t2[5] = selz(yp && xp, p[rp + cxp]);
        #pragma unroll
        for (int o = 0; o < OCG; ++o) {
            const float* wr = W + (o * CIN + ic) * 9;
            #pragma unroll
            for (int px = 0; px < 4; ++px) {
                float a = acc[o][px];
                a = fmaf(t0[px], wr[0], a); a = fmaf(t0[px+1], wr[1], a); a = fmaf(t0[px+2], wr[2], a);
                a = fmaf(t1[px], wr[3], a); a = fmaf(t1[px+1], wr[4], a); a = fmaf(t1[px+2], wr[5], a);
                a = fmaf(t2[px], wr[6], a); a = fmaf(t2[px+1], wr[7], a); a = fmaf(t2[px+2], wr[8], a);
                acc[o][px] = a;
            }
        }
    }
    float* out = g_ws + out_off + ((size_t)b * Cout + g * OCG) * 4096 + y * 64 + x0;
    #pragma unroll
    for (int o = 0; o < OCG; ++o) {
        float4 v;
        if (relu) {
            v.x = fmaxf(acc[o][0], 0.f); v.y = fmaxf(acc[o][1], 0.f);
            v.z = fmaxf(acc[o][2], 0.f); v.w = fmaxf(acc[o][3], 0.f);
        } else {
            v.x = acc[o][0]; v.y = acc[o][1]; v.z = acc[o][2]; v.w = acc[o][3];
        }
        *(float4*)(out + o * 4096) = v;
    }
}

// ---------------- fused softmax+moments over all 1024 (b,k) rows ----------------
__global__ void sm_mom2_k() {
    int bk = blockIdx.x;
    int app = (bk >= 512);
    float* row = g_ws + OFF_PARTS + (size_t)bk * 4096;
    float r[16];
    #pragma unroll
    for (int j = 0; j < 16; ++j) r[j] = row[threadIdx.x + j * 256];
    float m = r[0];
    #pragma unroll
    for (int j = 1; j < 16; ++j) m = fmaxf(m, r[j]);
    m = block_max(m);
    float s = 0.f;
    #pragma unroll
    for (int j = 0; j < 16; ++j) { r[j] = __expf(r[j] - m); s += r[j]; }
    s = block_sum(s);
    float inv = 1.0f / s;
    float sy = 0, sx = 0, syy = 0, sxy = 0, sxx = 0;
    #pragma unroll
    for (int j = 0; j < 16; ++j) {
        float pv = r[j] * inv;
        int i = threadIdx.x + j * 256;
        if (app) row[i] = pv;
        float gy = -1.0f + (i >> 6) * (2.0f / 63.0f);
        float gx = -1.0f + (i & 63) * (2.0f / 63.0f);
        sy += pv * gy; sx += pv * gx;
        syy += pv * gy * gy; sxy += pv * gy * gx; sxx += pv * gx * gx;
    }
    sy = block_sum(sy); sx = block_sum(sx);
    syy = block_sum(syy); sxy = block_sum(sxy); sxx = block_sum(sxx);
    if (threadIdx.x == 0) {
        float c00 = syy - sy * sy, c01 = sxy - sy * sx, c11 = sxx - sx * sx;
        float a = sqrtf(fmaxf(c00 + EPS, 1e-12f));
        float bb = c01 / (a + EPS);
        float cc = sqrtf(fmaxf(c11 - bb * bb, 0.f) + EPS);
        float det = a * cc;
        float sc = SCAL / (det + EPS);
        int idx = app ? (bk - 512) : bk;
        int mu_off = app ? OFF_MUA : OFF_MU;
        int linv_off = app ? OFF_LINVA : OFF_LINV;
        g_ws[mu_off + idx * 2 + 0] = sy;
        g_ws[mu_off + idx * 2 + 1] = sx;
        g_ws[linv_off + idx * 4 + 0] = cc * sc;
        g_ws[linv_off + idx * 4 + 1] = 0.f;
        g_ws[linv_off + idx * 4 + 2] = -bb * sc;
        g_ws[linv_off + idx * 4 + 3] = a * sc;
    }
}

// ---------------- alpha[b,k,f] = sum_hw fxs[b,f,hw] * parts[b,k,hw] ----------------
__global__ void alpha_k(int fxs_off, int parts_off) {
    int bk = blockIdx.x;
    int b = bk >> 4;
    float* alpha = g_ws + OFF_ALPHA;
    __shared__ float pl[4096];
    const float* pr = g_ws + parts_off + (size_t)bk * 4096;
    for (int i = threadIdx.x; i < 4096; i += 256) pl[i] = pr[i];
    __syncthreads();
    const float* fb = g_ws + fxs_off + (size_t)b * 32 * 4096;
    for (int f = 0; f < 32; ++f) {
        const float* fr = fb + f * 4096;
        float s = 0.f;
        for (int i = threadIdx.x; i < 4096; i += 256) s += fr[i] * pl[i];
        s = block_sum(s);
        if (threadIdx.x == 0) alpha[bk * 32 + f] = s;
    }
}

// ---------------- heat into enc ch[0..16), plus per-(b,k) sums ----------------
__global__ void heat_k(int mu_off, int linv_off, int enc_off) {
    int bk = blockIdx.x;
    int b = bk >> 4, k = bk & 15;
    float m0 = g_ws[mu_off + bk * 2], m1 = g_ws[mu_off + bk * 2 + 1];
    float L00 = g_ws[linv_off + bk * 4 + 0], L10 = g_ws[linv_off + bk * 4 + 2],
          L11 = g_ws[linv_off + bk * 4 + 3];
    float* out = g_ws + enc_off + ((size_t)b * 48 + k) * 4096;
    float s = 0.f;
    for (int i = threadIdx.x; i < 4096; i += 256) {
        float d0 = -1.0f + (i >> 6) * (2.0f / 63.0f) - m0;
        float d1 = -1.0f + (i & 63) * (2.0f / 63.0f) - m1;
        float p0 = d0 * L00 + d1 * L10;
        float p1 = d1 * L11;
        float h = 1.0f / (1.0f + p0 * p0 + p1 * p1);
        out[i] = h;
        s += h;
    }
    s = block_sum(s);
    if (threadIdx.x == 0) g_ws[OFF_HSUM + bk] = s;
}

// ---------------- fmap into enc ch[16..48) ----------------
__global__ void fmap_k(int enc_off) {
    int t = blockIdx.x;
    int tile = t & 15, bfi = t >> 4;
    int f = bfi & 31, b = bfi >> 5;
    __shared__ float coef[16];
    if (threadIdx.x < 16) {
        int k = threadIdx.x;
        coef[k] = g_ws[OFF_ALPHA + (b * 16 + k) * 32 + f] /
                  (g_ws[OFF_HSUM + b * 16 + k] + EPS);
    }
    __syncthreads();
    int pix = tile * 256 + threadIdx.x;
    const float* hb = g_ws + enc_off + (size_t)b * 48 * 4096 + pix;
    float acc = 0.f;
    for (int k = 0; k < 16; ++k) acc += hb[k * 4096] * coef[k];
    g_ws[enc_off + ((size_t)b * 48 + 16 + f) * 4096 + pix] = acc;
}

// ---------------- tiled decoder conv2 + fused 2x nearest upsample ----------------
__global__ void __launch_bounds__(256, 4)
conv_upmt_k(int in_off, int out_off) {
    int by = blockIdx.x & 15;
    int gb = blockIdx.x >> 4;
    int g = gb & 1, b = gb >> 1;
    int xq = threadIdx.x & 31, ry = threadIdx.x >> 5;
    int y = by * 8 + ry, x0 = xq * 4;
    const float* inb = g_ws + in_off + (size_t)b * 64 * 4096;
    const float* W = g_ws + W_DW2 + (size_t)(g * 16) * 576;
    float acc[16][4];
    #pragma unroll
    for (int o = 0; o < 16; ++o) {
        float bv = g_ws[W_DB2 + g * 16 + o];
        #pragma unroll
        for (int p = 0; p < 4; ++p) acc[o][p] = bv;
    }
    int m = x0 >> 1;
    bool vxm = x0 > 0, vxp = x0 < 124;
    int c0 = vxm ? m - 1 : 0, c1 = m, c2 = m + 1, c3 = vxp ? m + 2 : 63;
    bool yv0 = y > 0, yv2 = y < 127;
    int r0 = ((yv0 ? y - 1 : 0) >> 1) * 64;
    int r1 = (y >> 1) * 64;
    int r2 = ((yv2 ? y + 1 : 127) >> 1) * 64;
    for (int ic = 0; ic < 64; ++ic) {
        const float* p = inb + ic * 4096;
        float t0[6], t1[6], t2[6];
        {
            float L0 = p[r0 + c0], L1 = p[r0 + c1], L2 = p[r0 + c2], L3 = p[r0 + c3];
            t0[0] = selz(yv0 && vxm, L0);
            t0[1] = selz(yv0, L1); t0[2] = t0[1];
            t0[3] = selz(yv0, L2); t0[4] = t0[3];
            t0[5] = selz(yv0 && vxp, L3);
        }
        {
            float L0 = p[r1 + c0], L1 = p[r1 + c1], L2 = p[r1 + c2], L3 = p[r1 + c3];
            t1[0] = selz(vxm, L0);
            t1[1] = L1; t1[2] = L1;
            t1[3] = L2; t1[4] = L2;
            t1[5] = selz(vxp, L3);
        }
        {
            float L0 = p[r2 + c0], L1 = p[r2 + c1], L2 = p[r2 + c2], L3 = p[r2 + c3];
            t2[0] = selz(yv2 && vxm, L0);
            t2[1] = selz(yv2, L1); t2[2] = t2[1];
            t2[3] = selz(yv2, L2); t2[4] = t2[3];
            t2[5] = selz(yv2 && vxp, L3);
        }
        #pragma unroll
        for (int o = 0; o < 16; ++o) {
            const float* wr = W + (o * 64 + ic) * 9;
            #pragma unroll
            for (int px = 0; px < 4; ++px) {
                float a = acc[o][px];
                a = fmaf(t0[px], wr[0], a); a = fmaf(t0[px+1], wr[1], a); a = fmaf(t0[px+2], wr[2], a);
                a = fmaf(t1[px], wr[3], a); a = fmaf(t1[px+1], wr[4], a); a = fmaf(t1[px+2], wr[5], a);
                a = fmaf(t2[px], wr[6], a); a = fmaf(t2[px+1], wr[7], a); a = fmaf(t2[px+2], wr[8], a);
                acc[o][px] = a;
            }
        }
    }
    float* out = g_ws + out_off + ((size_t)b * 32 + g * 16) * 16384 + y * 128 + x0;
    #pragma unroll
    for (int o = 0; o < 16; ++o) {
        float4 v;
        v.x = fmaxf(acc[o][0], 0.f); v.y = fmaxf(acc[o][1], 0.f);
        v.z = fmaxf(acc[o][2], 0.f); v.w = fmaxf(acc[o][3], 0.f);
        *(float4*)(out + o * 16384) = v;
    }
}

// ---------------- tiled final conv + sigmoid -> out, fused rec-loss ----------------
__global__ void __launch_bounds__(256, 4)
conv_sigmt_k(int in_off, const void* __restrict__ ximg, void* __restrict__ outp) {
    int bf = g_isbf16;
    int by = blockIdx.x & 15;
    int b = blockIdx.x >> 4;
    int xq = threadIdx.x & 31, ry = threadIdx.x >> 5;
    int y = by * 8 + ry, x0 = xq * 4;
    const float* inb = g_ws + in_off + (size_t)b * 32 * 16384;
    const float* W = g_ws + W_DW3;
    float acc[3][4];
    #pragma unroll
    for (int o = 0; o < 3; ++o) {
        float bv = g_ws[W_DB3 + o];
        #pragma unroll
        for (int p = 0; p < 4; ++p) acc[o][p] = bv;
    }
    bool ym = y > 0, yp = y < 127, xm = x0 > 0, xp = x0 < 124;
    int rm = (ym ? y - 1 : 0) * 128, r0 = y * 128, rp = (yp ? y + 1 : 127) * 128;
    int cxm = xm ? x0 - 1 : 0, cxp = xp ? x0 + 4 : 127;
    for (int ic = 0; ic < 32; ++ic) {
        const float* p = inb + ic * 16384;
        float4 q0 = *(const float4*)(p + rm + x0);
        float4 q1 = *(const float4*)(p + r0 + x0);
        float4 q2 = *(const float4*)(p + rp + x0);
        float t0[6], t1[6], t2[6];
        t0[0] = selz(ym && xm, p[rm + cxm]);
        t0[1] = selz(ym, q0.x); t0[2] = selz(ym, q0.y);
        t0[3] = selz(ym, q0.z); t0[4] = selz(ym, q0.w);
        t0[5] = selz(ym && xp, p[rm + cxp]);
        t1[0] = selz(xm, p[r0 + cxm]);
        t1[1] = q1.x; t1[2] = q1.y; t1[3] = q1.z; t1[4] = q1.w;
        t1[5] = selz(xp, p[r0 + cxp]);
        t2[0] = selz(yp && xm, p[rp + cxm]);
        t2[1] = selz(yp, q2.x); t2[2] = selz(yp, q2.y);
        t2[3] = selz(yp, q2.z); t2[4] = selz(yp, q2.w);
        t2[5] = selz(yp && xp, p[rp + cxp]);
        #pragma unroll
        for (int o = 0; o < 3; ++o) {
            const float* wr = W + (o * 32 + ic) * 9;
            #pragma unroll
            for (int px = 0; px < 4; ++px) {
                float a = acc[o][px];
                a = fmaf(t0[px], wr[0], a); a = fmaf(t0[px+1], wr[1], a); a = fmaf(t0[px+2], wr[2], a);
                a = fmaf(t1[px], wr[3], a); a = fmaf(t1[px+1], wr[4], a); a = fmaf(t1[px+2], wr[5], a);
                a = fmaf(t2[px], wr[6], a); a = fmaf(t2[px+1], wr[7], a); a = fmaf(t2[px+2], wr[8], a);
                acc[o][px] = a;
            }
        }
    }
    float es = 0.f;
    #pragma unroll
    for (int o = 0; o < 3; ++o) {
        #pragma unroll
        for (int px = 0; px < 4; ++px) {
            float v = 1.0f / (1.0f + __expf(-acc[o][px]));
            size_t oidx = ((size_t)b * 3 + o) * 16384 + y * 128 + x0 + px;
            if (bf) ((__hip_bfloat16*)outp)[oidx] = __float2bfloat16(v);
            else    ((float*)outp)[oidx] = v;
            float e = ldin(ximg, oidx, bf) - v;
            es += e * e;
        }
    }
    float s = block_sum(es);
    if (threadIdx.x == 0) atomicAdd(&g_ws[OFF_REC], s);
}

// ---------------- scalar loss ----------------
__global__ void loss_k(const void* __restrict__ coord,
                       const void* __restrict__ vec,
                       void* __restrict__ outp) {
    int bf = g_isbf16;
    const float* mu = g_ws + OFF_MU;
    const float* linv = g_ws + OFF_LINV;
    const float* mu_a = g_ws + OFF_MUA;
    const float* linv_a = g_ws + OFF_LINVA;
    float s1 = 0, s2 = 0, s3 = 0;
    for (int i = threadIdx.x; i < 1024; i += 256) {
        float d = mu[i] - mu_a[i];
        s1 += d * d;
        float t = ldin(coord, i, bf) + ldin(vec, i, bf);
        float d3 = mu_a[i] - t;
        s3 += d3 * d3;
    }
    for (int i = threadIdx.x; i < 2048; i += 256) {
        float d = linv[i] - linv_a[i];
        s2 += d * d;
    }
    s1 = block_sum(s1);
    s2 = block_sum(s2);
    s3 = block_sum(s3);
    if (threadIdx.x == 0) {
        float loss = g_ws[OFF_REC] / 1572864.0f + s1 / 1024.0f + 0.01f * (s2 / 2048.0f)
                   + s3 / 1024.0f;
        if (bf) ((__hip_bfloat16*)outp)[1572864] = __float2bfloat16(loss);
        else    ((float*)outp)[1572864] = loss;
    }
}

extern "C" void kernel_launch(void* const* d_in, const int* in_sizes, int n_in,
                              void* d_out, int out_size, void* d_ws, size_t ws_size,
                              hipStream_t stream) {
    const void* x     = d_in[0];
    const void* x_st  = d_in[1];
    const void* x_at  = d_in[2];
    const void* coord = d_in[3];
    const void* vec   = d_in[4];

    dim3 blk(256);

    detect_k<<<1, 64, 0, stream>>>(x);
    wconv_k<<<64, blk, 0, stream>>>(
        d_in[5],  d_in[6],  d_in[7],  d_in[8],
        d_in[9],  d_in[10], d_in[11], d_in[12],
        d_in[13], d_in[14], d_in[15], d_in[16],
        d_in[17], d_in[18], d_in[19], d_in[20]);

    // ---- both encoder streams batched (B=64): conv1 -> X1(R3), conv2 -> X2(R1R2) ----
    conv_s2m2_k<<<64 * 4 * 16, blk, 0, stream>>>(x_at, x_st, OFF_X1);
    conv64t_k<64, 16><<<64 * 4 * 4, blk, 0, stream>>>(OFF_X1, W_ESW2, W_ESB2, OFF_X2, 4, 64, 1);
    conv64t_k<64, 8><<<64 * 2 * 4, blk, 0, stream>>>(OFF_X2, W_ESWP, W_ESBP, OFF_PARTS, 2, 16, 0);
    sm_mom2_k<<<1024, blk, 0, stream>>>();

    // ---- e_alpha(app_sum = X2 batches 32..63 = R2) -> f_xs (C2), then alpha ----
    conv64t_k<64, 8><<<32 * 8 * 4, blk, 0, stream>>>(OFF_APPH2, W_EAW1, W_EAB1, OFF_R1, 8, 64, 1);
    conv64t_k<64, 8><<<32 * 4 * 4, blk, 0, stream>>>(OFF_R1, W_EAW2, W_EAB2, OFF_C2, 4, 32, 0);
    alpha_k<<<512, blk, 0, stream>>>(OFF_C2, OFF_PARTSA);

    // ---- encoding into R1: heat (ch 0..15, shape mu/linv) + fmap (ch 16..47) ----
    heat_k<<<512, blk, 0, stream>>>(OFF_MU, OFF_LINV, OFF_R1);
    fmap_k<<<32 * 32 * 16, blk, 0, stream>>>(OFF_R1);

    // ---- decoder: E(R1) -> D1(R2) -> D2(R3) -> out ----
    conv64t_k<48, 8><<<32 * 8 * 4, blk, 0, stream>>>(OFF_R1, W_DW1, W_DB1, OFF_R2, 8, 64, 1);
    conv_upmt_k<<<32 * 2 * 16, blk, 0, stream>>>(OFF_R2, OFF_R3);
    conv_sigmt_k<<<32 * 16, blk, 0, stream>>>(OFF_R3, x, d_out);

    // ---- loss ----
    loss_k<<<1, blk, 0, stream>>>(coord, vec, d_out);
}

// Round 12
// 1198.799 us; speedup vs baseline: 7.5265x; 1.1683x over previous
//
#include <hip/hip_runtime.h>
#include <hip/hip_bf16.h>

#define EPS 1e-6f
#define SCAL 5.0f

// ---- static device scratch (zero-init BSS, graph-capture safe) ----
#define OFF_MU     0
#define OFF_LINV   1024
#define OFF_MUA    3072
#define OFF_LINVA  4096
#define OFF_HSUM   6144
#define OFF_ALPHA  6656
#define OFF_REC    23040
#define OFF_R1     294912
#define OFF_R2     (OFF_R1 + 8388608)
#define OFF_R3     (OFF_R2 + 8388608)
#define WS_TOTAL   (OFF_R3 + 16777216)

// B=64 batched staging (both streams; lifetimes verified):
#define OFF_X1     OFF_R3
#define OFF_X2     OFF_R1
#define OFF_APPH2  OFF_R2
#define OFF_PARTS  OFF_R3
#define OFF_PARTSA (OFF_R3 + 2097152)
#define OFF_C2     (OFF_R3 + 4194304)

// fp32 weight/bias offsets inside g_wt (filled by wconv_k).
// SEPARATE array from g_ws: conv kernels never write g_wt, so the compiler
// can prove no-alias and emit s_load (SGPR) for the wave-uniform weight
// reads — keeps the vector-memory pipe free for activation taps.
#define W_ESW1 0
#define W_ESB1 1728
#define W_ESW2 1792
#define W_ESB2 38656
#define W_ESWP 38720
#define W_ESBP 47936
#define W_EAW1 47952
#define W_EAB1 84816
#define W_EAW2 84880
#define W_EAB2 103312
#define W_DW1  103344
#define W_DB1  130992
#define W_DW2  131056
#define W_DB2  149488
#define W_DW3  149520
#define W_DB3  150384

__device__ __attribute__((aligned(16))) float g_ws[WS_TOTAL];
__device__ __attribute__((aligned(16))) float g_wt[150400];
__device__ int g_isbf16;

__device__ __forceinline__ float selz(bool c, float v) { return c ? v : 0.f; }

// runtime-dtype external load (adaptive pattern — required: fixed-dtype builds NaN'd)
__device__ __forceinline__ float ldin(const void* p, size_t i, int bf) {
    return bf ? __bfloat162float(((const __hip_bfloat16*)p)[i])
              : ((const float*)p)[i];
}

// ---------------- block reductions (blockDim.x == 256) ----------------
__device__ __forceinline__ float block_sum(float v) {
    __shared__ float sb[8];
    for (int off = 32; off; off >>= 1) v += __shfl_down(v, off, 64);
    int lane = threadIdx.x & 63, wid = threadIdx.x >> 6;
    __syncthreads();
    if (lane == 0) sb[wid] = v;
    __syncthreads();
    float r = 0.f;
    for (int i = 0; i < 4; ++i) r += sb[i];
    return r;
}

__device__ __forceinline__ float block_max(float v) {
    __shared__ float sb[8];
    for (int off = 32; off; off >>= 1) v = fmaxf(v, __shfl_down(v, off, 64));
    int lane = threadIdx.x & 63, wid = threadIdx.x >> 6;
    __syncthreads();
    if (lane == 0) sb[wid] = v;
    __syncthreads();
    float r = -1e30f;
    for (int i = 0; i < 4; ++i) r = fmaxf(r, sb[i]);
    return r;
}

// ---------------- dtype probe + init ----------------
__global__ void detect_k(const void* x) {
    const __hip_bfloat16* p = (const __hip_bfloat16*)x;
    int lane = threadIdx.x & 63;
    float v = 0.f;
    for (int i = lane; i < 256; i += 64) {
        float a = fabsf(__bfloat162float(p[i]));
        if (!(a <= 2.0f)) v = 1.f;          // catches big AND NaN
    }
    for (int off = 32; off; off >>= 1) v += __shfl_down(v, off, 64);
    if (lane == 0) {
        g_isbf16 = (v == 0.f) ? 1 : 0;
        g_ws[OFF_REC] = 0.f;
    }
}

// ---------------- weight prep: external dtype -> fp32 into g_wt ----------------
__global__ void wconv_k(const void* p0, const void* p1, const void* p2, const void* p3,
                        const void* p4, const void* p5, const void* p6, const void* p7,
                        const void* p8, const void* p9, const void* p10, const void* p11,
                        const void* p12, const void* p13, const void* p14, const void* p15) {
    int bf = g_isbf16;
    const void* ps[16] = {p0,p1,p2,p3,p4,p5,p6,p7,p8,p9,p10,p11,p12,p13,p14,p15};
    const int sz[16] = {1728,64,36864,64,9216,16,36864,64,18432,32,27648,64,18432,32,864,3};
    int gid = blockIdx.x * 256 + threadIdx.x, stride = gridDim.x * 256;
    int off = 0;
    for (int a = 0; a < 16; ++a) {
        const void* p = ps[a];
        for (int i = gid; i < sz[a]; i += stride)
            g_wt[off + i] = ldin(p, i, bf);
        off += sz[a];
    }
}

// ---------------- conv1 both streams: stride-2 -> fp32 [64,64,64,64], relu ----
__global__ void __launch_bounds__(256, 4)
conv_s2m2_k(const void* __restrict__ inA, const void* __restrict__ inB, int out_off) {
    int bf = g_isbf16;
    int tile = blockIdx.x & 15;
    int gb = blockIdx.x >> 4;
    int g = gb & 3, b = gb >> 2;
    const void* in = (b < 32) ? inA : inB;
    int bb = b & 31;
    int pix = tile * 256 + threadIdx.x;
    int y = pix >> 6, x = pix & 63;
    size_t inb = (size_t)bb * 3 * 16384;
    const float* W = g_wt + W_ESW1 + (size_t)(g * 16) * 27;
    float acc[16];
    #pragma unroll
    for (int o = 0; o < 16; ++o) acc[o] = g_wt[W_ESB1 + g * 16 + o];
    int iy0 = 2 * y, ix0 = 2 * x;
    bool my2 = (iy0 + 2 < 128), mx2 = (ix0 + 2 < 128);
    int iy2 = my2 ? iy0 + 2 : 127, ix2 = mx2 ? ix0 + 2 : 127;
    for (int ic = 0; ic < 3; ++ic) {
        size_t pb = inb + ic * 16384;
        float t[9];
        t[0] = ldin(in, pb + iy0 * 128 + ix0, bf);
        t[1] = ldin(in, pb + iy0 * 128 + ix0 + 1, bf);
        t[2] = selz(mx2, ldin(in, pb + iy0 * 128 + ix2, bf));
        t[3] = ldin(in, pb + (iy0 + 1) * 128 + ix0, bf);
        t[4] = ldin(in, pb + (iy0 + 1) * 128 + ix0 + 1, bf);
        t[5] = selz(mx2, ldin(in, pb + (iy0 + 1) * 128 + ix2, bf));
        t[6] = selz(my2, ldin(in, pb + iy2 * 128 + ix0, bf));
        t[7] = selz(my2, ldin(in, pb + iy2 * 128 + ix0 + 1, bf));
        t[8] = selz(my2 && mx2, ldin(in, pb + iy2 * 128 + ix2, bf));
        #pragma unroll
        for (int o = 0; o < 16; ++o) {
            const float* wr = W + (o * 3 + ic) * 9;
            float a = acc[o];
            #pragma unroll
            for (int j = 0; j < 9; ++j) a = fmaf(t[j], wr[j], a);
            acc[o] = a;
        }
    }
    float* out = g_ws + out_off + ((size_t)b * 64 + g * 16) * 4096 + pix;
    #pragma unroll
    for (int o = 0; o < 16; ++o) out[o * 4096] = fmaxf(acc[o], 0.f);
}

// ---------------- tiled 3x3 SAME conv on 64x64 planes: 1x4 px x OCG ocs per thread ----
template<int CIN, int OCG>
__global__ void __launch_bounds__(256, 4)
conv64t_k(int in_off, int w_off, int b_off, int out_off, int ng, int Cout, int relu) {
    int by = blockIdx.x & 3;
    int gb = blockIdx.x >> 2;
    int g = gb % ng, b = gb / ng;
    int xq = threadIdx.x & 15, ry = threadIdx.x >> 4;
    int y = by * 16 + ry, x0 = xq * 4;
    const float* inb = g_ws + in_off + (size_t)b * CIN * 4096;
    const float* W = g_wt + w_off + (size_t)(g * OCG) * CIN * 9;
    float acc[OCG][4];
    #pragma unroll
    for (int o = 0; o < OCG; ++o) {
        float bv = g_wt[b_off + g * OCG + o];
        #pragma unroll
        for (int p = 0; p < 4; ++p) acc[o][p] = bv;
    }
    bool ym = y > 0, yp = y < 63, xm = x0 > 0, xp = x0 < 60;
    int rm = (ym ? y - 1 : 0) * 64, r0 = y * 64, rp = (yp ? y + 1 : 63) * 64;
    int cxm = xm ? x0 - 1 : 0, cxp = xp ? x0 + 4 : 63;
    for (int ic = 0; ic < CIN; ++ic) {
        const float* p = inb + ic * 4096;
        float4 q0 = *(const float4*)(p + rm + x0);
        float4 q1 = *(const float4*)(p + r0 + x0);
        float4 q2 = *(const float4*)(p + rp + x0);
        float t0[6], t1[6], t2[6];
        t0[0] = selz(ym && xm, p[rm + cxm]);
        t0[1] = selz(ym, q0.x); t0[2] = selz(ym, q0.y);
        t0[3] = selz(ym, q0.z); t0[4] = selz(ym, q0.w);
        t0[5] = selz(ym && xp, p[rm + cxp]);
        t1[0] = selz(xm, p[r0 + cxm]);
        t1[1] = q1.x; t1[2] = q1.y; t1[3] = q1.z; t1[4] = q1.w;
        t1[5] = selz(xp, p[r0 + cxp]);
        t2[0] = selz(yp && xm, p[rp + cxm]);
        t2[1] = selz(yp, q2.x); t2[2] = selz(yp, q2.y);
        t2[3] = selz(yp, q2.z); t2[4] = selz(yp, q2.w);
        t2[5] = selz(yp && xp, p[rp + cxp]);
        #pragma unroll
        for (int o = 0; o < OCG; ++o) {
            const float* wr = W + (o * CIN + ic) * 9;
            #pragma unroll
            for (int px = 0; px < 4; ++px) {
                float a = acc[o][px];
                a = fmaf(t0[px], wr[0], a); a = fmaf(t0[px+1], wr[1], a); a = fmaf(t0[px+2], wr[2], a);
                a = fmaf(t1[px], wr[3], a); a = fmaf(t1[px+1], wr[4], a); a = fmaf(t1[px+2], wr[5], a);
                a = fmaf(t2[px], wr[6], a); a = fmaf(t2[px+1], wr[7], a); a = fmaf(t2[px+2], wr[8], a);
                acc[o][px] = a;
            }
        }
    }
    float* out = g_ws + out_off + ((size_t)b * Cout + g * OCG) * 4096 + y * 64 + x0;
    #pragma unroll
    for (int o = 0; o < OCG; ++o) {
        float4 v;
        if (relu) {
            v.x = fmaxf(acc[o][0], 0.f); v.y = fmaxf(acc[o][1], 0.f);
            v.z = fmaxf(acc[o][2], 0.f); v.w = fmaxf(acc[o][3], 0.f);
        } else {
            v.x = acc[o][0]; v.y = acc[o][1]; v.z = acc[o][2]; v.w = acc[o][3];
        }
        *(float4*)(out + o * 4096) = v;
    }
}

// ---------------- fused softmax+moments over all 1024 (b,k) rows ----------------
__global__ void sm_mom2_k() {
    int bk = blockIdx.x;
    int app = (bk >= 512);
    float* row = g_ws + OFF_PARTS + (size_t)bk * 4096;
    float r[16];
    #pragma unroll
    for (int j = 0; j < 16; ++j) r[j] = row[threadIdx.x + j * 256];
    float m = r[0];
    #pragma unroll
    for (int j = 1; j < 16; ++j) m = fmaxf(m, r[j]);
    m = block_max(m);
    float s = 0.f;
    #pragma unroll
    for (int j = 0; j < 16; ++j) { r[j] = __expf(r[j] - m); s += r[j]; }
    s = block_sum(s);
    float inv = 1.0f / s;
    float sy = 0, sx = 0, syy = 0, sxy = 0, sxx = 0;
    #pragma unroll
    for (int j = 0; j < 16; ++j) {
        float pv = r[j] * inv;
        int i = threadIdx.x + j * 256;
        if (app) row[i] = pv;
        float gy = -1.0f + (i >> 6) * (2.0f / 63.0f);
        float gx = -1.0f + (i & 63) * (2.0f / 63.0f);
        sy += pv * gy; sx += pv * gx;
        syy += pv * gy * gy; sxy += pv * gy * gx; sxx += pv * gx * gx;
    }
    sy = block_sum(sy); sx = block_sum(sx);
    syy = block_sum(syy); sxy = block_sum(sxy); sxx = block_sum(sxx);
    if (threadIdx.x == 0) {
        float c00 = syy - sy * sy, c01 = sxy - sy * sx, c11 = sxx - sx * sx;
        float a = sqrtf(fmaxf(c00 + EPS, 1e-12f));
        float bb = c01 / (a + EPS);
        float cc = sqrtf(fmaxf(c11 - bb * bb, 0.f) + EPS);
        float det = a * cc;
        float sc = SCAL / (det + EPS);
        int idx = app ? (bk - 512) : bk;
        int mu_off = app ? OFF_MUA : OFF_MU;
        int linv_off = app ? OFF_LINVA : OFF_LINV;
        g_ws[mu_off + idx * 2 + 0] = sy;
        g_ws[mu_off + idx * 2 + 1] = sx;
        g_ws[linv_off + idx * 4 + 0] = cc * sc;
        g_ws[linv_off + idx * 4 + 1] = 0.f;
        g_ws[linv_off + idx * 4 + 2] = -bb * sc;
        g_ws[linv_off + idx * 4 + 3] = a * sc;
    }
}

// ---------------- alpha[b,k,f] = sum_hw fxs[b,f,hw] * parts[b,k,hw] ----------------
__global__ void alpha_k(int fxs_off, int parts_off) {
    int bk = blockIdx.x;
    int b = bk >> 4;
    float* alpha = g_ws + OFF_ALPHA;
    __shared__ float pl[4096];
    const float* pr = g_ws + parts_off + (size_t)bk * 4096;
    for (int i = threadIdx.x; i < 4096; i += 256) pl[i] = pr[i];
    __syncthreads();
    const float* fb = g_ws + fxs_off + (size_t)b * 32 * 4096;
    for (int f = 0; f < 32; ++f) {
        const float* fr = fb + f * 4096;
        float s = 0.f;
        for (int i = threadIdx.x; i < 4096; i += 256) s += fr[i] * pl[i];
        s = block_sum(s);
        if (threadIdx.x == 0) alpha[bk * 32 + f] = s;
    }
}

// ---------------- heat into enc ch[0..16), plus per-(b,k) sums ----------------
__global__ void heat_k(int mu_off, int linv_off, int enc_off) {
    int bk = blockIdx.x;
    int b = bk >> 4, k = bk & 15;
    float m0 = g_ws[mu_off + bk * 2], m1 = g_ws[mu_off + bk * 2 + 1];
    float L00 = g_ws[linv_off + bk * 4 + 0], L10 = g_ws[linv_off + bk * 4 + 2],
          L11 = g_ws[linv_off + bk * 4 + 3];
    float* out = g_ws + enc_off + ((size_t)b * 48 + k) * 4096;
    float s = 0.f;
    for (int i = threadIdx.x; i < 4096; i += 256) {
        float d0 = -1.0f + (i >> 6) * (2.0f / 63.0f) - m0;
        float d1 = -1.0f + (i & 63) * (2.0f / 63.0f) - m1;
        float p0 = d0 * L00 + d1 * L10;
        float p1 = d1 * L11;
        float h = 1.0f / (1.0f + p0 * p0 + p1 * p1);
        out[i] = h;
        s += h;
    }
    s = block_sum(s);
    if (threadIdx.x == 0) g_ws[OFF_HSUM + bk] = s;
}

// ---------------- fmap into enc ch[16..48) ----------------
__global__ void fmap_k(int enc_off) {
    int t = blockIdx.x;
    int tile = t & 15, bfi = t >> 4;
    int f = bfi & 31, b = bfi >> 5;
    __shared__ float coef[16];
    if (threadIdx.x < 16) {
        int k = threadIdx.x;
        coef[k] = g_ws[OFF_ALPHA + (b * 16 + k) * 32 + f] /
                  (g_ws[OFF_HSUM + b * 16 + k] + EPS);
    }
    __syncthreads();
    int pix = tile * 256 + threadIdx.x;
    const float* hb = g_ws + enc_off + (size_t)b * 48 * 4096 + pix;
    float acc = 0.f;
    for (int k = 0; k < 16; ++k) acc += hb[k * 4096] * coef[k];
    g_ws[enc_off + ((size_t)b * 48 + 16 + f) * 4096 + pix] = acc;
}

// ---------------- tiled decoder conv2 + fused 2x nearest upsample ----------------
__global__ void __launch_bounds__(256, 4)
conv_upmt_k(int in_off, int out_off) {
    int by = blockIdx.x & 15;
    int gb = blockIdx.x >> 4;
    int g = gb & 1, b = gb >> 1;
    int xq = threadIdx.x & 31, ry = threadIdx.x >> 5;
    int y = by * 8 + ry, x0 = xq * 4;
    const float* inb = g_ws + in_off + (size_t)b * 64 * 4096;
    const float* W = g_wt + W_DW2 + (size_t)(g * 16) * 576;
    float acc[16][4];
    #pragma unroll
    for (int o = 0; o < 16; ++o) {
        float bv = g_wt[W_DB2 + g * 16 + o];
        #pragma unroll
        for (int p = 0; p < 4; ++p) acc[o][p] = bv;
    }
    int m = x0 >> 1;
    bool vxm = x0 > 0, vxp = x0 < 124;
    int c0 = vxm ? m - 1 : 0, c1 = m, c2 = m + 1, c3 = vxp ? m + 2 : 63;
    bool yv0 = y > 0, yv2 = y < 127;
    int r0 = ((yv0 ? y - 1 : 0) >> 1) * 64;
    int r1 = (y >> 1) * 64;
    int r2 = ((yv2 ? y + 1 : 127) >> 1) * 64;
    for (int ic = 0; ic < 64; ++ic) {
        const float* p = inb + ic * 4096;
        float t0[6], t1[6], t2[6];
        {
            float L0 = p[r0 + c0], L1 = p[r0 + c1], L2 = p[r0 + c2], L3 = p[r0 + c3];
            t0[0] = selz(yv0 && vxm, L0);
            t0[1] = selz(yv0, L1); t0[2] = t0[1];
            t0[3] = selz(yv0, L2); t0[4] = t0[3];
            t0[5] = selz(yv0 && vxp, L3);
        }
        {
            float L0 = p[r1 + c0], L1 = p[r1 + c1], L2 = p[r1 + c2], L3 = p[r1 + c3];
            t1[0] = selz(vxm, L0);
            t1[1] = L1; t1[2] = L1;
            t1[3] = L2; t1[4] = L2;
            t1[5] = selz(vxp, L3);
        }
        {
            float L0 = p[r2 + c0], L1 = p[r2 + c1], L2 = p[r2 + c2], L3 = p[r2 + c3];
            t2[0] = selz(yv2 && vxm, L0);
            t2[1] = selz(yv2, L1); t2[2] = t2[1];
            t2[3] = selz(yv2, L2); t2[4] = t2[3];
            t2[5] = selz(yv2 && vxp, L3);
        }
        #pragma unroll
        for (int o = 0; o < 16; ++o) {
            const float* wr = W + (o * 64 + ic) * 9;
            #pragma unroll
            for (int px = 0; px < 4; ++px) {
                float a = acc[o][px];
                a = fmaf(t0[px], wr[0], a); a = fmaf(t0[px+1], wr[1], a); a = fmaf(t0[px+2], wr[2], a);
                a = fmaf(t1[px], wr[3], a); a = fmaf(t1[px+1], wr[4], a); a = fmaf(t1[px+2], wr[5], a);
                a = fmaf(t2[px], wr[6], a); a = fmaf(t2[px+1], wr[7], a); a = fmaf(t2[px+2], wr[8], a);
                acc[o][px] = a;
            }
        }
    }
    float* out = g_ws + out_off + ((size_t)b * 32 + g * 16) * 16384 + y * 128 + x0;
    #pragma unroll
    for (int o = 0; o < 16; ++o) {
        float4 v;
        v.x = fmaxf(acc[o][0], 0.f); v.y = fmaxf(acc[o][1], 0.f);
        v.z = fmaxf(acc[o][2], 0.f); v.w = fmaxf(acc[o][3], 0.f);
        *(float4*)(out + o * 16384) = v;
    }
}

// ---------------- tiled final conv + sigmoid -> out, fused rec-loss ----------------
__global__ void __launch_bounds__(256, 4)
conv_sigmt_k(int in_off, const void* __restrict__ ximg, void* __restrict__ outp) {
    int bf = g_isbf16;
    int by = blockIdx.x & 15;
    int b = blockIdx.x >> 4;
    int xq = threadIdx.x & 31, ry = threadIdx.x >> 5;
    int y = by * 8 + ry, x0 = xq * 4;
    const float* inb = g_ws + in_off + (size_t)b * 32 * 16384;
    const float* W = g_wt + W_DW3;
    float acc[3][4];
    #pragma unroll
    for (int o = 0; o < 3; ++o) {
        float bv = g_wt[W_DB3 + o];
        #pragma unroll
        for (int p = 0; p < 4; ++p) acc[o][p] = bv;
    }
    bool ym = y > 0, yp = y < 127, xm = x0 > 0, xp = x0 < 124;
    int rm = (ym ? y - 1 : 0) * 128, r0 = y * 128, rp = (yp ? y + 1 : 127) * 128;
    int cxm = xm ? x0 - 1 : 0, cxp = xp ? x0 + 4 : 127;
    for (int ic = 0; ic < 32; ++ic) {
        const float* p = inb + ic * 16384;
        float4 q0 = *(const float4*)(p + rm + x0);
        float4 q1 = *(const float4*)(p + r0 + x0);
        float4 q2 = *(const float4*)(p + rp + x0);
        float t0[6], t1[6], t2[6];
        t0[0] = selz(ym && xm, p[rm + cxm]);
        t0[1] = selz(ym, q0.x); t0[2] = selz(ym, q0.y);
        t0[3] = selz(ym, q0.z); t0[4] = selz(ym, q0.w);
        t0[5] = selz(ym && xp, p[rm + cxp]);
        t1[0] = selz(xm, p[r0 + cxm]);
        t1[1] = q1.x; t1[2] = q1.y; t1[3] = q1.z; t1[4] = q1.w;
        t1[5] = selz(xp, p[r0 + cxp]);
        t2[0] = selz(yp && xm, p[rp + cxm]);
        t2[1] = selz(yp, q2.x); t2[2] = selz(yp, q2.y);
        t2[3] = selz(yp, q2.z); t2[4] = selz(yp, q2.w);
        t2[5] = selz(yp && xp, p[rp + cxp]);
        #pragma unroll
        for (int o = 0; o < 3; ++o) {
            const float* wr = W + (o * 32 + ic) * 9;
            #pragma unroll
            for (int px = 0; px < 4; ++px) {
                float a = acc[o][px];
                a = fmaf(t0[px], wr[0], a); a = fmaf(t0[px+1], wr[1], a); a = fmaf(t0[px+2], wr[2], a);
                a = fmaf(t1[px], wr[3], a); a = fmaf(t1[px+1], wr[4], a); a = fmaf(t1[px+2], wr[5], a);
                a = fmaf(t2[px], wr[6], a); a = fmaf(t2[px+1], wr[7], a); a = fmaf(t2[px+2], wr[8], a);
                acc[o][px] = a;
            }
        }
    }
    float es = 0.f;
    #pragma unroll
    for (int o = 0; o < 3; ++o) {
        #pragma unroll
        for (int px = 0; px < 4; ++px) {
            float v = 1.0f / (1.0f + __expf(-acc[o][px]));
            size_t oidx = ((size_t)b * 3 + o) * 16384 + y * 128 + x0 + px;
            if (bf) ((__hip_bfloat16*)outp)[oidx] = __float2bfloat16(v);
            else    ((float*)outp)[oidx] = v;
            float e = ldin(ximg, oidx, bf) - v;
            es += e * e;
        }
    }
    float s = block_sum(es);
    if (threadIdx.x == 0) atomicAdd(&g_ws[OFF_REC], s);
}

// ---------------- scalar loss ----------------
__global__ void loss_k(const void* __restrict__ coord,
                       const void* __restrict__ vec,
                       void* __restrict__ outp) {
    int bf = g_isbf16;
    const float* mu = g_ws + OFF_MU;
    const float* linv = g_ws + OFF_LINV;
    const float* mu_a = g_ws + OFF_MUA;
    const float* linv_a = g_ws + OFF_LINVA;
    float s1 = 0, s2 = 0, s3 = 0;
    for (int i = threadIdx.x; i < 1024; i += 256) {
        float d = mu[i] - mu_a[i];
        s1 += d * d;
        float t = ldin(coord, i, bf) + ldin(vec, i, bf);
        float d3 = mu_a[i] - t;
        s3 += d3 * d3;
    }
    for (int i = threadIdx.x; i < 2048; i += 256) {
        float d = linv[i] - linv_a[i];
        s2 += d * d;
    }
    s1 = block_sum(s1);
    s2 = block_sum(s2);
    s3 = block_sum(s3);
    if (threadIdx.x == 0) {
        float loss = g_ws[OFF_REC] / 1572864.0f + s1 / 1024.0f + 0.01f * (s2 / 2048.0f)
                   + s3 / 1024.0f;
        if (bf) ((__hip_bfloat16*)outp)[1572864] = __float2bfloat16(loss);
        else    ((float*)outp)[1572864] = loss;
    }
}

extern "C" void kernel_launch(void* const* d_in, const int* in_sizes, int n_in,
                              void* d_out, int out_size, void* d_ws, size_t ws_size,
                              hipStream_t stream) {
    const void* x     = d_in[0];
    const void* x_st  = d_in[1];
    const void* x_at  = d_in[2];
    const void* coord = d_in[3];
    const void* vec   = d_in[4];

    dim3 blk(256);

    detect_k<<<1, 64, 0, stream>>>(x);
    wconv_k<<<64, blk, 0, stream>>>(
        d_in[5],  d_in[6],  d_in[7],  d_in[8],
        d_in[9],  d_in[10], d_in[11], d_in[12],
        d_in[13], d_in[14], d_in[15], d_in[16],
        d_in[17], d_in[18], d_in[19], d_in[20]);

    // ---- both encoder streams batched (B=64): conv1 -> X1(R3), conv2 -> X2(R1R2) ----
    conv_s2m2_k<<<64 * 4 * 16, blk, 0, stream>>>(x_at, x_st, OFF_X1);
    conv64t_k<64, 16><<<64 * 4 * 4, blk, 0, stream>>>(OFF_X1, W_ESW2, W_ESB2, OFF_X2, 4, 64, 1);
    conv64t_k<64, 8><<<64 * 2 * 4, blk, 0, stream>>>(OFF_X2, W_ESWP, W_ESBP, OFF_PARTS, 2, 16, 0);
    sm_mom2_k<<<1024, blk, 0, stream>>>();

    // ---- e_alpha(app_sum = X2 batches 32..63 = R2) -> f_xs (C2), then alpha ----
    conv64t_k<64, 8><<<32 * 8 * 4, blk, 0, stream>>>(OFF_APPH2, W_EAW1, W_EAB1, OFF_R1, 8, 64, 1);
    conv64t_k<64, 8><<<32 * 4 * 4, blk, 0, stream>>>(OFF_R1, W_EAW2, W_EAB2, OFF_C2, 4, 32, 0);
    alpha_k<<<512, blk, 0, stream>>>(OFF_C2, OFF_PARTSA);

    // ---- encoding into R1: heat (ch 0..15, shape mu/linv) + fmap (ch 16..47) ----
    heat_k<<<512, blk, 0, stream>>>(OFF_MU, OFF_LINV, OFF_R1);
    fmap_k<<<32 * 32 * 16, blk, 0, stream>>>(OFF_R1);

    // ---- decoder: E(R1) -> D1(R2) -> D2(R3) -> out ----
    conv64t_k<48, 8><<<32 * 8 * 4, blk, 0, stream>>>(OFF_R1, W_DW1, W_DB1, OFF_R2, 8, 64, 1);
    conv_upmt_k<<<32 * 2 * 16, blk, 0, stream>>>(OFF_R2, OFF_R3);
    conv_sigmt_k<<<32 * 16, blk, 0, stream>>>(OFF_R3, x, d_out);

    // ---- loss ----
    loss_k<<<1, blk, 0, stream>>>(coord, vec, d_out);
}